// Round 13
// baseline (551.852 us; speedup 1.0000x reference)
//
#include <hip/hip_runtime.h>
#include <math.h>

using u16 = unsigned short;
using u32 = unsigned int;
using u64 = unsigned long long;
using bf16x8 = __attribute__((ext_vector_type(8))) short;
using f32x4  = __attribute__((ext_vector_type(4))) float;

#define C_DIM   512
#define HEADS   8
#define HDIM    64
#define P_DIM   64
#define A_TOK   256
#define VCAP    256
#define S_TOK   512
#define NWIN    64
#define NROW    32768      // NWIN * S_TOK (window-slot space)
#define NPATCH  16384      // NWIN * A_TOK
#define NUNIQ   6144       // 4096 patch + 2048 voxel unique tokens
#define MLP_DIM 2048
#define NV_TOT  2048
#define LOG2E   1.44269504088896f

__device__ __forceinline__ float bf2f(u16 b) { return __uint_as_float(((u32)b) << 16); }
__device__ __forceinline__ u16 f2bf(float f) {
    u32 u = __float_as_uint(f);
    return (u16)((u + 0x7fffu + ((u >> 16) & 1u)) >> 16);   // RNE
}
// HW packed f32->bf16 RNE: dst.lo = bf16(lo), dst.hi = bf16(hi). 1 inst replaces ~8.
__device__ __forceinline__ u32 cvtpk(float lo, float hi) {
    u32 r;
    asm("v_cvt_pk_bf16_f32 %0, %1, %2" : "=v"(r) : "v"(lo), "v"(hi));
    return r;
}
__device__ __forceinline__ float4 bf4f(ushort4 v) {
    return make_float4(bf2f(v.x), bf2f(v.y), bf2f(v.z), bf2f(v.w));
}
// dtype-agnostic loads from RAW inputs: isbf=1 -> bf16, else f32
__device__ __forceinline__ float ldf(const void* p, size_t e, int isbf) {
    return isbf ? bf2f(((const u16*)p)[e]) : ((const float*)p)[e];
}
__device__ __forceinline__ float4 ld4(const void* p, size_t e, int isbf) {  // e % 4 == 0
    if (isbf) return bf4f(*(const ushort4*)((const u16*)p + e));
    return *(const float4*)((const float*)p + e);
}
// async global->LDS, 16B per lane; lds dest must be wave-uniform-base + lane*16
__device__ __forceinline__ void gload16(const u16* g, u16* l) {
    __builtin_amdgcn_global_load_lds(
        (const __attribute__((address_space(1))) u32*)g,
        (__attribute__((address_space(3))) u32*)l, 16, 0, 0);
}
// tanh-form GELU via sigmoid, log2e folded into poly, v_rcp instead of exact div.
// x*sigmoid(1.5957691x + 0.0713548x^3); |err| <= ~3e-4 (approx dominates rcp's ~1e-7)
__device__ __forceinline__ float fast_gelu(float x) {
    float x2 = x * x;
    float z = x * (-2.3021083f - 0.10294323f * x2);   // = -(1.5957691 + 0.0713548 x^2)*log2e
    float e = exp2f(z);                               // v_exp_f32
    return x * __builtin_amdgcn_rcpf(1.f + e);        // v_rcp_f32
}
// per-block dtype self-detection: vote on low-16-bits-as-bf16 plausibility (L2-resident scan)
__device__ __forceinline__ int self_detect(const u32* patch, int tid, int* sm)
{
    int cnt = 0;
    for (int i = tid; i < 4096; i += 256) {
        u32 w = patch[i];
        float a = fabsf(__uint_as_float((w & 0xffffu) << 16));
        if (a > 1e-8f && a < 1e4f) cnt++;
    }
    sm[tid] = cnt;
    __syncthreads();
    for (int o = 128; o; o >>= 1) { if (tid < o) sm[tid] += sm[tid + o]; __syncthreads(); }
    int r = (sm[0] > 2458) ? 1 : 0;
    __syncthreads();
    return r;
}

// ------- merged setup: weight transposes + voxel select/tokidx/validk + bias prep + flag -------
// blocks 0..3071: wtrans; 3072..3135: per-window meta (tokidx, validk, wcnt); 3136..3141: bias.
// tokidx[n*512+s] = unique-token row (0..6143) feeding window n slot s (0 if invalid; masked).
__global__ __launch_bounds__(256) void setup_kernel(
    const void* __restrict__ wq, const void* __restrict__ wk,
    const void* __restrict__ wv, const void* __restrict__ wo,
    const void* __restrict__ w1, const void* __restrict__ w2,
    const void* __restrict__ bq, const void* __restrict__ bk, const void* __restrict__ bv,
    const void* __restrict__ patch,
    const int* __restrict__ vy, const int* __restrict__ vx,
    u16* __restrict__ wqkvT, u16* __restrict__ woT,
    u16* __restrict__ w1T, u16* __restrict__ w2T,
    float* __restrict__ bqkv, u16* __restrict__ tokidx, unsigned char* __restrict__ validk,
    int* __restrict__ wcnt, int* __restrict__ flagp)
{
    __shared__ int sm[256];
    __shared__ u16 tile[32][33];
    int tx = threadIdx.x, ty = threadIdx.y;          // block (32,8)
    int tid = ty * 32 + tx;
    int isbf = self_detect((const u32*)patch, tid, sm);
    int bid = blockIdx.x;
    if (bid == 0 && tid == 0) *flagp = isbf;

    if (bid < 3072) {
        int id = bid;
        const void* in; u16* out; int K, N; float sc = 1.f;
        if (id < 256)       { in = wq; out = wqkvT;              K = 512;  N = 512;  sc = 0.125f * LOG2E; }
        else if (id < 512)  { id -= 256;  in = wk; out = wqkvT + 512 * 512;  K = 512;  N = 512; }
        else if (id < 768)  { id -= 512;  in = wv; out = wqkvT + 1024 * 512; K = 512;  N = 512; }
        else if (id < 1024) { id -= 768;  in = wo; out = woT;    K = 512;  N = 512; }
        else if (id < 2048) { id -= 1024; in = w1; out = w1T;    K = 512;  N = 2048; }
        else                { id -= 2048; in = w2; out = w2T;    K = 2048; N = 512; }
        int ntx = N >> 5;
        int n0 = (id % ntx) * 32, k0 = (id / ntx) * 32;
        #pragma unroll
        for (int i = 0; i < 4; i++)
            tile[ty + i * 8][tx] = f2bf(sc * ldf(in, (size_t)(k0 + ty + i * 8) * N + (n0 + tx), isbf));
        __syncthreads();
        #pragma unroll
        for (int i = 0; i < 4; i++)
            out[(size_t)(n0 + ty + i * 8) * K + (k0 + tx)] = tile[tx][ty + i * 8];
    } else if (bid < 3136) {
        if (tid < 64) {                               // first wave only (64-lane ballot)
            int n = bid - 3072, lane = tid;
            int y0 = (n >> 3) << 3, x0 = (n & 7) << 3;
            int count = 0;
            for (int base = 0; base < NV_TOT; base += 64) {
                int v = base + lane;
                int yy = vy[v], xx = vx[v];
                bool m = (yy >= y0) && (yy < y0 + 16) && (xx >= x0) && (xx < x0 + 16);
                u64 mask = __ballot(m);
                int pos = count + __popcll(mask & ((1ull << lane) - 1ull));
                if (m && pos < VCAP) tokidx[n * S_TOK + A_TOK + pos] = (u16)(4096 + v);
                count += __popcll(mask);
            }
            int cn = count < VCAP ? count : VCAP;
            for (int j = lane; j < VCAP; j += 64) {
                if (j >= cn) tokidx[n * S_TOK + A_TOK + j] = 0;
                validk[n * S_TOK + A_TOK + j] = (j < cn) ? 1 : 0;
            }
            for (int s = lane; s < A_TOK; s += 64) {  // patch slots
                int iy = ((n >> 3) << 3) + (s >> 4);
                int ix = ((n & 7) << 3) + (s & 15);
                bool val = (iy < P_DIM) && (ix < P_DIM);
                tokidx[n * S_TOK + s] = val ? (u16)(iy * P_DIM + ix) : 0;
                validk[n * S_TOK + s] = val ? 1 : 0;
            }
            if (lane == 0) wcnt[n] = cn;
        }
    } else {
        int t = (bid - 3136) * 256 + tid;             // q bias pre-scaled incl. log2(e)
        if (t < 512)       bqkv[t] = 0.125f * LOG2E * ldf(bq, t, isbf);
        else if (t < 1024) bqkv[t] = ldf(bk, t - 512, isbf);
        else if (t < 1536) bqkv[t] = ldf(bv, t - 1024, isbf);
    }
}

// ---------------- LN1 over UNIQUE tokens -> hU (bf16): rows 0..4095 patch, 4096..6143 voxel ----
__global__ __launch_bounds__(256) void ln1u_kernel(
    const void* __restrict__ patch, const void* __restrict__ vox,
    const void* __restrict__ g, const void* __restrict__ b,
    const int* __restrict__ flagp,
    u16* __restrict__ h)
{
    int isbf = *flagp;
    int r = blockIdx.x * 4 + (threadIdx.x >> 6);    // one wave per unique token
    int lane = threadIdx.x & 63;
    const void* tok = (r < 4096) ? patch : vox;
    size_t base = (r < 4096) ? (size_t)r * C_DIM : (size_t)(r - 4096) * C_DIM;
    float4 xa = ld4(tok, base + lane * 4, isbf);
    float4 xb = ld4(tok, base + 256 + lane * 4, isbf);
    float sum = xa.x + xa.y + xa.z + xa.w + xb.x + xb.y + xb.z + xb.w;
    float sq  = xa.x * xa.x + xa.y * xa.y + xa.z * xa.z + xa.w * xa.w
              + xb.x * xb.x + xb.y * xb.y + xb.z * xb.z + xb.w * xb.w;
    #pragma unroll
    for (int off = 32; off; off >>= 1) {
        sum += __shfl_xor(sum, off, 64);
        sq  += __shfl_xor(sq,  off, 64);
    }
    float mean = sum * (1.f / C_DIM);
    float var  = fmaxf(sq * (1.f / C_DIM) - mean * mean, 0.f);
    float rstd = rsqrtf(var + 1e-5f);
    float4 ga = ld4(g, lane * 4, isbf);
    float4 gb = ld4(g, 256 + lane * 4, isbf);
    float4 ba = ld4(b, lane * 4, isbf);
    float4 bb = ld4(b, 256 + lane * 4, isbf);
    uint2 wa, wb;
    wa.x = cvtpk((xa.x - mean) * rstd * ga.x + ba.x, (xa.y - mean) * rstd * ga.y + ba.y);
    wa.y = cvtpk((xa.z - mean) * rstd * ga.z + ba.z, (xa.w - mean) * rstd * ga.w + ba.w);
    wb.x = cvtpk((xb.x - mean) * rstd * gb.x + bb.x, (xb.y - mean) * rstd * gb.y + bb.y);
    wb.y = cvtpk((xb.z - mean) * rstd * gb.z + bb.z, (xb.w - mean) * rstd * gb.w + bb.w);
    ((uint2*)(h + (size_t)r * C_DIM))[lane]      = wa;
    ((uint2*)(h + (size_t)r * C_DIM))[lane + 64] = wb;
}

// ---------------- LN2 over bf16 rows -> bf16 ----------------
__global__ __launch_bounds__(256) void ln2_kernel(
    const u16* __restrict__ x,
    const void* __restrict__ g, const void* __restrict__ b,
    const int* __restrict__ flagp,
    u16* __restrict__ h2)
{
    int isbf = *flagp;
    int r = blockIdx.x * 4 + (threadIdx.x >> 6);
    int lane = threadIdx.x & 63;
    const u16* src = x + (size_t)r * C_DIM;
    float4 xa = bf4f(((const ushort4*)src)[lane]);
    float4 xb = bf4f(((const ushort4*)src)[lane + 64]);
    float sum = xa.x + xa.y + xa.z + xa.w + xb.x + xb.y + xb.z + xb.w;
    float sq  = xa.x * xa.x + xa.y * xa.y + xa.z * xa.z + xa.w * xa.w
              + xb.x * xb.x + xb.y * xb.y + xb.z * xb.z + xb.w * xb.w;
    #pragma unroll
    for (int off = 32; off; off >>= 1) {
        sum += __shfl_xor(sum, off, 64);
        sq  += __shfl_xor(sq,  off, 64);
    }
    float mean = sum * (1.f / C_DIM);
    float var  = fmaxf(sq * (1.f / C_DIM) - mean * mean, 0.f);
    float rstd = rsqrtf(var + 1e-5f);
    float4 ga = ld4(g, lane * 4, isbf);
    float4 gb = ld4(g, 256 + lane * 4, isbf);
    float4 ba = ld4(b, lane * 4, isbf);
    float4 bb = ld4(b, 256 + lane * 4, isbf);
    uint2 wa, wb;
    wa.x = cvtpk((xa.x - mean) * rstd * ga.x + ba.x, (xa.y - mean) * rstd * ga.y + ba.y);
    wa.y = cvtpk((xa.z - mean) * rstd * ga.z + ba.z, (xa.w - mean) * rstd * ga.w + ba.w);
    wb.x = cvtpk((xb.x - mean) * rstd * gb.x + bb.x, (xb.y - mean) * rstd * gb.y + bb.y);
    wb.y = cvtpk((xb.z - mean) * rstd * gb.z + bb.z, (xb.w - mean) * rstd * gb.w + bb.w);
    ((uint2*)(h2 + (size_t)r * C_DIM))[lane]      = wa;
    ((uint2*)(h2 + (size_t)r * C_DIM))[lane + 64] = wb;
}

// ---------------- generic bf16 MFMA GEMM: C = op(A @ B^T + bias), one TM x 128 tile/block -----
// Single-buffer 2-barrier K-loop (best measured structure at these short-K shapes).
// TM = tile rows (128 or 64). TM=64 halves per-block resources -> ~2x blocks/CU for the
// low-residency N=512 GEMMs (WO, MLP2). vtb path requires TM=128 (QKV only).
// __launch_bounds__ min-waves (measured win, r9): TM=128 -> 3 waves/SIMD; TM=64 -> 4.
#define GF_GELU      2
#define GF_RES_BF16  8    // += res (bf16, [M][N])
#define GF_RES_PATCH 16   // += gathered patch token (raw dtype), valid positions only
#define GF_QKV       32   // UNIQUE-token qkv: N=1536 -> q [4096][512] / k [6144][512] / v^T [512][6144]
#define GF_PATCHM    64   // m rows are compact patch rows: skip fully-OOB edge tiles

template<int FLAGS, int TM>
__global__ __launch_bounds__(256, TM == 64 ? 4 : 3) void gemm_kernel(
    const u16* __restrict__ A, const u16* __restrict__ BT,
    const void* __restrict__ bias,
    void* __restrict__ Cout, void* __restrict__ Cout2, void* __restrict__ Cout3,
    const void* __restrict__ resv,
    const int* __restrict__ flagp,
    int M, int N, int K, int ldc)
{
    constexpr int AI  = TM / 32;          // a-frag count per wave (4 or 2)
    constexpr int TMW = TM / 2;           // rows per wave-row-half (64 or 32)
    __shared__ u16 smem[(TM + 128) * 64]; // A tile TM*64 + B tile 128*64 (u16); epilogue reuse
    int tid = threadIdx.x;
    int nt, mt;
    int gx = gridDim.x, gy = gridDim.y;
    if ((gy & 7) == 0) {
        // XCD-local remap: linear id L (x fastest), xcd = L % 8 (round-robin heuristic).
        int L = blockIdx.x + gx * blockIdx.y;
        int c = L & 7, s = L >> 3;
        mt = c * (gy >> 3) + s / gx;
        nt = s % gx;
    } else { nt = blockIdx.x; mt = blockIdx.y; }
    int m0 = mt * TM, n0 = nt << 7;
    int region = (FLAGS & GF_QKV) ? (nt >> 2) : 0;   // 0:q 1:k 2:v^T
    if constexpr (FLAGS & GF_QKV) {
        if (region == 0 && m0 >= 4096) return;       // q only for unique patch tokens
    }
    if constexpr (FLAGS & GF_PATCHM) {
        constexpr int TPW = 256 / TM;                 // tiles per window
        int n = mt / TPW;                             // window index
        int lo = (mt % TPW) * TM;                     // first local row
        if ((n >> 3) == 7 && lo >= 128) return;       // fully-OOB edge tile, rows never consumed
    }
    int isbf = 0;
    if constexpr ((FLAGS & (GF_RES_PATCH)) || (!(FLAGS & GF_QKV))) isbf = *flagp;
    int w = tid >> 6, lane = tid & 63;
    int wr = (w >> 1) * TMW, wc = (w & 1) * 64;
    int l16 = lane & 15, quad = lane >> 4;
    u16* As = smem;
    u16* Bs = smem + TM * 64;
    bool vtb = (FLAGS & GF_QKV) && (region == 2);   // transposed-output block (TM=128 only)

    f32x4 acc[AI][4];
    #pragma unroll
    for (int i = 0; i < AI; i++)
        #pragma unroll
        for (int j = 0; j < 4; j++) { acc[i][j][0] = 0.f; acc[i][j][1] = 0.f; acc[i][j][2] = 0.f; acc[i][j][3] = 0.f; }

    int swz = (l16 & 7);                   // frag-read chunk swizzle key
    const u16* Xs = vtb ? Bs : As;         // first operand rows -> D rows
    const u16* Ys = vtb ? As : Bs;
    for (int k0 = 0; k0 < K; k0 += 64) {
        #pragma unroll
        for (int it = 0; it < AI; it++) {      // A: TM*8 chunk slots
            int c = (it * 4 + w) * 64 + lane;
            int row = c >> 3, phys = c & 7;
            int kc = phys ^ (row & 7);          // XOR swizzle: break 128B-stride bank aliasing
            gload16(A + (size_t)(m0 + row) * K + k0 + kc * 8, As + (size_t)c * 8);
        }
        #pragma unroll
        for (int it = 0; it < 4; it++) {        // B: 1024 chunk slots
            int c = (it * 4 + w) * 64 + lane;
            int row = c >> 3, phys = c & 7;
            int kc = phys ^ (row & 7);
            gload16(BT + (size_t)(n0 + row) * K + k0 + kc * 8, Bs + (size_t)c * 8);
        }
        __syncthreads();
        #pragma unroll
        for (int ks = 0; ks < 2; ks++) {
            bf16x8 a[AI], b[4];
            #pragma unroll
            for (int i = 0; i < AI; i++) {
                int chunk = (ks * 4 + quad) ^ swz;
                a[i] = *(const bf16x8*)&Xs[(wr + i * 16 + l16) * 64 + chunk * 8];
            }
            #pragma unroll
            for (int j = 0; j < 4; j++) {
                int chunk = (ks * 4 + quad) ^ swz;
                b[j] = *(const bf16x8*)&Ys[(wc + j * 16 + l16) * 64 + chunk * 8];
            }
            #pragma unroll
            for (int i = 0; i < AI; i++)
                #pragma unroll
                for (int j = 0; j < 4; j++)
                    acc[i][j] = __builtin_amdgcn_mfma_f32_16x16x32_bf16(a[i], b[j], acc[i][j], 0, 0, 0);
        }
        __syncthreads();
    }

    // ---------- epilogue (bf16 via cvt_pk, LDS-staged, coalesced 128B rows) ----------
    u16* st = smem + w * (TMW * 64);    // per-wave TMW x 64 bf16 stage (reuses tile LDS)
    #pragma unroll
    for (int i = 0; i < AI; i++) {
        #pragma unroll
        for (int j = 0; j < 4; j++) {
            int gcol = n0 + wc + j * 16 + l16;
            float bc = 0.f;
            if constexpr (FLAGS & GF_QKV) { if (!vtb) bc = ((const float*)bias)[gcol]; }
            else if (bias) bc = ldf(bias, gcol, isbf);
            float vv[4];
            #pragma unroll
            for (int r2 = 0; r2 < 4; r2++) {
                int lrow = wr + i * 16 + quad * 4 + r2;
                int grow = m0 + lrow;
                if (vtb) bc = ((const float*)bias)[n0 + lrow];   // channel-indexed bias
                float v = acc[i][j][r2] + bc;
                if constexpr (FLAGS & GF_GELU) v = fast_gelu(v);
                if constexpr (FLAGS & GF_RES_BF16) v += bf2f(((const u16*)resv)[(size_t)grow * N + gcol]);
                if constexpr (FLAGS & GF_RES_PATCH) {
                    int nn = grow >> 8, s = grow & 255;
                    int iy = ((nn >> 3) << 3) + (s >> 4);
                    int ix = ((nn & 7) << 3) + (s & 15);
                    if (iy < P_DIM && ix < P_DIM)
                        v += ldf(resv, (size_t)(iy * P_DIM + ix) * C_DIM + gcol, isbf);
                }
                vv[r2] = v;
            }
            u32 p01 = cvtpk(vv[0], vv[1]);
            u32 p23 = cvtpk(vv[2], vv[3]);
            int sb = (i * 16 + quad * 4) * 64 + j * 16 + l16;
            st[sb]       = (u16)p01;
            st[sb + 64]  = (u16)(p01 >> 16);
            st[sb + 128] = (u16)p23;
            st[sb + 192] = (u16)(p23 >> 16);
        }
    }
    asm volatile("" ::: "memory");   // same-wave LDS: block reorder, no barrier needed
    u16* cdst; int cst;
    if constexpr (FLAGS & GF_QKV) {
        if (region == 0) {          // q: unique patch-token rows, pre-scaled
            cst = 512;
            cdst = (u16*)Cout  + (size_t)(m0 + wr) * 512 + (n0 + wc);
        } else if (region == 1) {   // k: unique-token rows
            cst = 512;
            cdst = (u16*)Cout2 + (size_t)(m0 + wr) * 512 + (n0 - 512 + wc);
        } else {                    // v^T: rows = channels, cols = unique tokens
            cst = NUNIQ;
            cdst = (u16*)Cout3 + (size_t)(n0 - 1024 + wr) * NUNIQ + (m0 + wc);
        }
    } else {
        cst = ldc;
        cdst = (u16*)Cout + (size_t)(m0 + wr) * ldc + (n0 + wc);
    }
    #pragma unroll
    for (int rr = 0; rr < TM / 16; rr++) {
        int row = rr * 8 + (lane >> 3);
        uint4 val = *(const uint4*)&st[row * 64 + (lane & 7) * 8];
        *(uint4*)(cdst + (size_t)row * cst + (lane & 7) * 8) = val;   // 128B/row coalesced
    }
}

// ---------------- expand V^T unique -> window-major V^T [512][32768] ----------------
// d uniform per block -> vTU row (12KB) stays L1-resident; writes coalesced 16B/lane.
__global__ __launch_bounds__(256) void expandv_kernel(
    const u16* __restrict__ vTU, const u16* __restrict__ tokidx,
    u16* __restrict__ vtt)
{
    int gid = blockIdx.x * 256 + threadIdx.x;   // one uint4 (8 slots) per thread
    int d = gid >> 12;                          // 4096 chunks per channel row
    int c = gid & 4095;
    int n = c >> 6, s0 = (c & 63) * 8;
    const u16* tp = tokidx + n * S_TOK + s0;
    ushort4 ta = *(const ushort4*)tp;
    ushort4 tb = *(const ushort4*)(tp + 4);
    const u16* vr = vTU + (size_t)d * NUNIQ;
    uint4 val;
    val.x = (u32)vr[ta.x] | ((u32)vr[ta.y] << 16);
    val.y = (u32)vr[ta.z] | ((u32)vr[ta.w] << 16);
    val.z = (u32)vr[tb.x] | ((u32)vr[tb.y] << 16);
    val.w = (u32)vr[tb.z] | ((u32)vr[tb.w] << 16);
    *(uint4*)(vtt + (size_t)d * NROW + n * S_TOK + s0) = val;
}

// ---------------- flash attention per (window, head); patch queries only ----------------
// Q read at unique-token rows; K gathered per-lane from kU via tokidx (gload16 src is per-lane);
// V from window-major vtt. scores in log2 domain (log2e folded into q scale).
// __launch_bounds__(256, 3): cap VGPR at 170 (was 208 -> 2 waves/SIMD). Kernel is latency-
// exposed (no pipe >33%, all blocks co-resident); +50% waves/SIMD is the untested TLP lever.
__global__ __launch_bounds__(256, 3) void attn_kernel(
    const u16* __restrict__ q, const u16* __restrict__ kU, const u16* __restrict__ vtg,
    const u16* __restrict__ tokidx,
    const unsigned char* __restrict__ validk, const int* __restrict__ wcnt,
    u16* __restrict__ o)
{
    __shared__ u16 sK[64 * 64];          // [key][d], DMA-gathered, swizzled chunks
    __shared__ u16 sV[64 * 64];          // [d][key], DMA-staged from V^T, swizzled chunks
    __shared__ u16 sP[4 * 64 * 64];      // per-wave P tile, chunk-swizzled (48KB total LDS)
    int h = blockIdx.x, n = blockIdx.y;
    int tid = threadIdx.x;
    int w = tid >> 6, lane = tid & 63;
    int l16 = lane & 15, quad = lane >> 4;
    int swz = (l16 & 7);
    int cnt = wcnt[n];                   // valid voxel slots in this window

    // prefetch this lane's K-row token ids for all 8 key-tiles (8 lanes share a row -> broadcast)
    int rowA = tid >> 3;                 // staging row for it=0 (c = tid)
    u16 tokA[8], tokB[8];
    #pragma unroll
    for (int t = 0; t < 8; t++) {
        tokA[t] = tokidx[n * S_TOK + t * 64 + rowA];
        tokB[t] = tokidx[n * S_TOK + t * 64 + 32 + rowA];
    }

    bf16x8 qf[4][2];
    #pragma unroll
    for (int i = 0; i < 4; i++)
        #pragma unroll
        for (int ks = 0; ks < 2; ks++) {
            int tok = tokidx[n * S_TOK + w * 64 + i * 16 + l16];   // patch slots (<256)
            int col = h * HDIM + ks * 32 + quad * 8;
            qf[i][ks] = *(const bf16x8*)(q + (size_t)tok * C_DIM + col);
        }

    f32x4 oacc[4][4];
    float lsum[4][4];
    #pragma unroll
    for (int i = 0; i < 4; i++)
        #pragma unroll
        for (int j = 0; j < 4; j++) {
            oacc[i][j][0] = 0.f; oacc[i][j][1] = 0.f; oacc[i][j][2] = 0.f; oacc[i][j][3] = 0.f;
            lsum[i][j] = 0.f;
        }

    for (int ktile = 0; ktile < 8; ktile++) {
        // voxel key-tiles past the valid count are entirely masked -> skip (block-uniform, monotone)
        if (ktile >= 4 && cnt <= (ktile - 4) * 64) break;
        __syncthreads();                       // prior tile's readers done before overwrite
        #pragma unroll
        for (int it = 0; it < 2; it++) {
            int c = it * 256 + w * 64 + lane;  // 0..511 chunk slots
            int row = c >> 3, phys = c & 7;
            int kc = phys ^ (row & 7);
            int tok = (it == 0) ? tokA[ktile] : tokB[ktile];
            gload16(kU + (size_t)tok * C_DIM + h * HDIM + kc * 8, sK + (size_t)c * 8);
            gload16(vtg + (size_t)(h * HDIM + row) * (size_t)NROW + n * S_TOK + ktile * 64 + kc * 8,
                    sV + (size_t)c * 8);
        }
        __syncthreads();

        f32x4 sacc[4][4];
        #pragma unroll
        for (int i = 0; i < 4; i++)
            #pragma unroll
            for (int j = 0; j < 4; j++) { sacc[i][j][0] = 0.f; sacc[i][j][1] = 0.f; sacc[i][j][2] = 0.f; sacc[i][j][3] = 0.f; }
        #pragma unroll
        for (int ks = 0; ks < 2; ks++) {
            int chunk = (ks * 4 + quad) ^ swz;
            bf16x8 bfr[4];
            #pragma unroll
            for (int j = 0; j < 4; j++) bfr[j] = *(const bf16x8*)&sK[(j * 16 + l16) * 64 + chunk * 8];
            #pragma unroll
            for (int i = 0; i < 4; i++)
                #pragma unroll
                for (int j = 0; j < 4; j++)
                    sacc[i][j] = __builtin_amdgcn_mfma_f32_16x16x32_bf16(qf[i][ks], bfr[j], sacc[i][j], 0, 0, 0);
        }

        bool kvalid[4];
        #pragma unroll
        for (int j = 0; j < 4; j++)
            kvalid[j] = validk[n * S_TOK + ktile * 64 + j * 16 + l16] != 0;

        #pragma unroll
        for (int i = 0; i < 4; i++)
            #pragma unroll
            for (int r2 = 0; r2 < 4; r2++) {
                int prow = i * 16 + quad * 4 + r2;
                float pv[4];
                #pragma unroll
                for (int j = 0; j < 4; j++) {
                    pv[j] = kvalid[j] ? exp2f(sacc[i][j][r2]) : 0.f;
                    lsum[i][r2] += pv[j];
                }
                #pragma unroll
                for (int jp = 0; jp < 2; jp++) {
                    u32 pk = cvtpk(pv[2 * jp], pv[2 * jp + 1]);
                    int col0 = (2 * jp) * 16 + l16;
                    int col1 = col0 + 16;
                    int base_ = (w * 64 + prow) * 64;
                    sP[base_ + (((col0 >> 3) ^ (prow & 7)) << 3) + (col0 & 7)] = (u16)pk;
                    sP[base_ + (((col1 >> 3) ^ (prow & 7)) << 3) + (col1 & 7)] = (u16)(pk >> 16);
                }
            }
        asm volatile("" ::: "memory");   // per-wave LDS: forbid read-before-write reorder
        #pragma unroll
        for (int ks = 0; ks < 2; ks++) {
            int chunk = (ks * 4 + quad) ^ swz;
            bf16x8 pa[4], vb[4];
            #pragma unroll
            for (int i = 0; i < 4; i++)   pa[i]  = *(const bf16x8*)&sP[(w * 64 + i * 16 + l16) * 64 + chunk * 8];
            #pragma unroll
            for (int jd = 0; jd < 4; jd++) vb[jd] = *(const bf16x8*)&sV[(jd * 16 + l16) * 64 + chunk * 8];
            #pragma unroll
            for (int i = 0; i < 4; i++)
                #pragma unroll
                for (int jd = 0; jd < 4; jd++)
                    oacc[i][jd] = __builtin_amdgcn_mfma_f32_16x16x32_bf16(pa[i], vb[jd], oacc[i][jd], 0, 0, 0);
        }
    }

    // normalize, stage O per-wave in LDS, coalesced 128B stores
    asm volatile("" ::: "memory");
    __syncthreads();                     // all waves done with sP/sV before O staging reuse
    u16* ost = sP + w * 4096;            // flat 64x64 region, stride 64 (sP data dead)
    #pragma unroll
    for (int i = 0; i < 4; i++) {
        #pragma unroll
        for (int r2 = 0; r2 < 4; r2++) {
            float l = lsum[i][r2];
            #pragma unroll
            for (int off = 8; off; off >>= 1)
                l += __shfl_xor(l, off, 64);
            float inv = (l > 0.f) ? 1.f / l : 0.f;
            int ob_ = (i * 16 + quad * 4 + r2) * 64 + l16;
            u32 q01 = cvtpk(oacc[i][0][r2] * inv, oacc[i][1][r2] * inv);
            u32 q23 = cvtpk(oacc[i][2][r2] * inv, oacc[i][3][r2] * inv);
            ost[ob_]      = (u16)q01;
            ost[ob_ + 16] = (u16)(q01 >> 16);
            ost[ob_ + 32] = (u16)q23;
            ost[ob_ + 48] = (u16)(q23 >> 16);
        }
    }
    asm volatile("" ::: "memory");
    u16* obase = o + (size_t)(n * A_TOK + w * 64) * C_DIM + h * HDIM;
    #pragma unroll
    for (int rr = 0; rr < 8; rr++) {
        int row = rr * 8 + (lane >> 3);
        uint4 val = *(const uint4*)&ost[row * 64 + (lane & 7) * 8];
        *(uint4*)(obase + (size_t)row * C_DIM + (lane & 7) * 8) = val;
    }
}

// ---------------- final gather-average (bf16 input) ----------------
__global__ __launch_bounds__(256) void gather_kernel(const u16* __restrict__ xf,
                                                     void* __restrict__ out,
                                                     const int* __restrict__ flagp)
{
    int isbf = *flagp;
    int gid = blockIdx.x * 256 + threadIdx.x;    // pixel*128 + 4-elem chunk
    int p = gid >> 7, cv = gid & 127;
    int py = p >> 6, px = p & 63;
    float4 acc = make_float4(0.f, 0.f, 0.f, 0.f);
    int cnt = 0;
    #pragma unroll
    for (int dy = 0; dy < 2; dy++) {
        int y0 = ((py >> 3) - dy) << 3;
        if (y0 < 0) continue;
        #pragma unroll
        for (int dx = 0; dx < 2; dx++) {
            int x0 = ((px >> 3) - dx) << 3;
            if (x0 < 0) continue;
            int n = ((y0 >> 3) << 3) + (x0 >> 3);
            int s = (py - y0) * 16 + (px - x0);
            float4 t = bf4f(((const ushort4*)(xf + (size_t)(n * A_TOK + s) * C_DIM))[cv]);
            acc.x += t.x; acc.y += t.y; acc.z += t.z; acc.w += t.w;
            cnt++;
        }
    }
    float inv = 1.f / (float)cnt;
    acc.x *= inv; acc.y *= inv; acc.z *= inv; acc.w *= inv;
    if (isbf) {
        uint2 o;
        o.x = cvtpk(acc.x, acc.y);
        o.y = cvtpk(acc.z, acc.w);
        ((uint2*)out)[gid] = o;
    } else {
        ((float4*)out)[gid] = acc;
    }
}

extern "C" void kernel_launch(void* const* d_in, const int* in_sizes, int n_in,
                              void* d_out, int out_size, void* d_ws, size_t ws_size,
                              hipStream_t stream)
{
    const void* patch = d_in[0];
    const void* vox   = d_in[1];
    const void* ln1g  = d_in[2];
    const void* ln1b  = d_in[3];
    const void* wq = d_in[4];  const void* bq = d_in[5];
    const void* wk = d_in[6];  const void* bk = d_in[7];
    const void* wv = d_in[8];  const void* bv = d_in[9];
    const void* wo = d_in[10]; const void* bo = d_in[11];
    const void* ln2g = d_in[12];
    const void* ln2b = d_in[13];
    const void* w1 = d_in[14]; const void* b1 = d_in[15];
    const void* w2 = d_in[16]; const void* b2 = d_in[17];
    const int* vpy = (const int*)d_in[18];
    const int* vpx = (const int*)d_in[19];

    const size_t MB = 1ull << 20;
    char* ws = (char*)d_ws;
    if (ws_size < 128 * MB) return;   // insufficient workspace -> visible failure

    // unique-token buffers (all dead before tbuf is written at MLP1)
    u16*  hU    = (u16*)(ws + 0);          // [6144][512] bf16, 6MB
    u16*  kU    = (u16*)(ws + 6 * MB);     // [6144][512] bf16, 6MB   (live thru attn)
    u16*  vTU   = (u16*)(ws + 12 * MB);    // [512][6144] bf16, 6MB   (dead after expand)
    u16*  qU    = (u16*)(ws + 18 * MB);    // [4096][512] bf16, 4MB   (live thru attn)
    u16*  vtt   = (u16*)(ws + 22 * MB);    // window V^T [512][32768] bf16, 32MB (live thru attn)
    u16*  tbuf  = (u16*)(ws + 0);          // [16384][2048] bf16, 64MB (MLP1->MLP2; overlays 0..54MB)
    u16*  obuf  = (u16*)(ws + 64 * MB);    // [16384][512] bf16, 16MB (attn->WO)
    u16*  xfbuf = (u16*)(ws + 64 * MB);    // 16MB (MLP2 out; obuf dead by then)
    u16*  xbuf16 = (u16*)(ws + 80 * MB);   // x residual, 16MB (WO->MLP2)
    u16*  h2buf = (u16*)(ws + 96 * MB);    // 16MB (ln2->MLP1)
    u16* wqkvT = (u16*)(ws + 112 * MB);    // [1536][512] bf16, 1.5MB (q rows pre-scaled)
    u16* woT  = (u16*)(ws + 114 * MB);     // [512][512], 0.5MB
    u16* w1T  = (u16*)(ws + 115 * MB);     // [2048][512], 2MB
    u16* w2T  = (u16*)(ws + 117 * MB);     // [512][2048], 2MB
    u16* tokidx = (u16*)(ws + 119 * MB);   // [32768] u16, 64KB
    unsigned char* validk = (unsigned char*)(ws + 119 * MB + 64 * 1024); // 32KB
    int* flagp = (int*)(ws + 119 * MB + 128 * 1024);
    float* bqkv = (float*)(ws + 119 * MB + 132 * 1024);  // [1536] f32
    int* wcnt = (int*)(ws + 119 * MB + 140 * 1024);      // [64] valid-voxel counts

    // merged setup: wtrans (3072) + per-window meta (64) + bias prep (6)
    setup_kernel<<<3142, dim3(32, 8), 0, stream>>>(wq, wk, wv, wo, w1, w2, bq, bk, bv,
        patch, vpy, vpx, wqkvT, woT, w1T, w2T, bqkv, tokidx, validk, wcnt, flagp);

    // LN1 on 6144 unique tokens only (was 32768 window slots)
    ln1u_kernel<<<NUNIQ / 4, 256, 0, stream>>>(patch, vox, ln1g, ln1b, flagp, hU);

    // fused QKV on unique tokens: M=6144, N=1536 -> grid (12, 48), XCD-local remap
    gemm_kernel<GF_QKV, 128><<<dim3(12, NUNIQ / 128), 256, 0, stream>>>(hU, wqkvT, bqkv,
        qU, kU, vTU, nullptr, flagp, NUNIQ, 1536, 512, 512);

    // expand V^T to window-major (only V needs materialized window layout)
    expandv_kernel<<<(C_DIM * NROW / 8) / 256, 256, 0, stream>>>(vTU, tokidx, vtt);

    // attn: best-measured config + LB(256,3) occupancy push (the one untested attn lever)
    attn_kernel<<<dim3(HEADS, NWIN), 256, 0, stream>>>(qU, kU, vtt, tokidx, validk, wcnt, obuf);

    // x = tokens(patch gather) + o @ wo + bo  -- TM=64: grid (4,256) = ~3.75 blocks/CU
    gemm_kernel<GF_RES_PATCH | GF_PATCHM, 64><<<dim3(4, NPATCH / 64), 256, 0, stream>>>(obuf, woT, bo,
        xbuf16, nullptr, nullptr, patch, flagp, NPATCH, 512, 512, 512);

    ln2_kernel<<<NPATCH / 4, 256, 0, stream>>>(xbuf16, ln2g, ln2b, flagp, h2buf);

    // MLP1: TM=128, launch-bounds min 3 waves/SIMD (measured: drops MLP1 out of top-5)
    gemm_kernel<GF_GELU | GF_PATCHM, 128><<<dim3(16, NPATCH / 128), 256, 0, stream>>>(h2buf, w1T, b1,
        tbuf, nullptr, nullptr, nullptr, flagp, NPATCH, 2048, 512, 2048);

    // MLP2: TM=64
    gemm_kernel<GF_RES_BF16 | GF_PATCHM, 64><<<dim3(4, NPATCH / 64), 256, 0, stream>>>(tbuf, w2T, b2,
        xfbuf, nullptr, nullptr, xbuf16, flagp, NPATCH, 512, 2048, 512);

    gather_kernel<<<(4096 * 128) / 256, 256, 0, stream>>>(xfbuf, d_out, flagp);
}

// Round 14
// 342.513 us; speedup vs baseline: 1.6112x; 1.6112x over previous
//
#include <hip/hip_runtime.h>
#include <math.h>

using u16 = unsigned short;
using u32 = unsigned int;
using u64 = unsigned long long;
using bf16x8 = __attribute__((ext_vector_type(8))) short;
using f32x4  = __attribute__((ext_vector_type(4))) float;

#define C_DIM   512
#define HEADS   8
#define HDIM    64
#define P_DIM   64
#define A_TOK   256
#define VCAP    256
#define S_TOK   512
#define NWIN    64
#define NROW    32768      // NWIN * S_TOK (window-slot space)
#define NPATCH  16384      // NWIN * A_TOK
#define NUNIQ   6144       // 4096 patch + 2048 voxel unique tokens
#define MLP_DIM 2048
#define NV_TOT  2048
#define LOG2E   1.44269504088896f

__device__ __forceinline__ float bf2f(u16 b) { return __uint_as_float(((u32)b) << 16); }
__device__ __forceinline__ u16 f2bf(float f) {
    u32 u = __float_as_uint(f);
    return (u16)((u + 0x7fffu + ((u >> 16) & 1u)) >> 16);   // RNE
}
// HW packed f32->bf16 RNE: dst.lo = bf16(lo), dst.hi = bf16(hi). 1 inst replaces ~8.
__device__ __forceinline__ u32 cvtpk(float lo, float hi) {
    u32 r;
    asm("v_cvt_pk_bf16_f32 %0, %1, %2" : "=v"(r) : "v"(lo), "v"(hi));
    return r;
}
__device__ __forceinline__ float4 bf4f(ushort4 v) {
    return make_float4(bf2f(v.x), bf2f(v.y), bf2f(v.z), bf2f(v.w));
}
// dtype-agnostic loads from RAW inputs: isbf=1 -> bf16, else f32
__device__ __forceinline__ float ldf(const void* p, size_t e, int isbf) {
    return isbf ? bf2f(((const u16*)p)[e]) : ((const float*)p)[e];
}
__device__ __forceinline__ float4 ld4(const void* p, size_t e, int isbf) {  // e % 4 == 0
    if (isbf) return bf4f(*(const ushort4*)((const u16*)p + e));
    return *(const float4*)((const float*)p + e);
}
// async global->LDS, 16B per lane; lds dest must be wave-uniform-base + lane*16
__device__ __forceinline__ void gload16(const u16* g, u16* l) {
    __builtin_amdgcn_global_load_lds(
        (const __attribute__((address_space(1))) u32*)g,
        (__attribute__((address_space(3))) u32*)l, 16, 0, 0);
}
// tanh-form GELU via sigmoid, log2e folded into poly, v_rcp instead of exact div.
// x*sigmoid(1.5957691x + 0.0713548x^3); |err| <= ~3e-4 (approx dominates rcp's ~1e-7)
__device__ __forceinline__ float fast_gelu(float x) {
    float x2 = x * x;
    float z = x * (-2.3021083f - 0.10294323f * x2);   // = -(1.5957691 + 0.0713548 x^2)*log2e
    float e = exp2f(z);                               // v_exp_f32
    return x * __builtin_amdgcn_rcpf(1.f + e);        // v_rcp_f32
}
// per-block dtype self-detection: vote on low-16-bits-as-bf16 plausibility (L2-resident scan)
__device__ __forceinline__ int self_detect(const u32* patch, int tid, int* sm)
{
    int cnt = 0;
    for (int i = tid; i < 4096; i += 256) {
        u32 w = patch[i];
        float a = fabsf(__uint_as_float((w & 0xffffu) << 16));
        if (a > 1e-8f && a < 1e4f) cnt++;
    }
    sm[tid] = cnt;
    __syncthreads();
    for (int o = 128; o; o >>= 1) { if (tid < o) sm[tid] += sm[tid + o]; __syncthreads(); }
    int r = (sm[0] > 2458) ? 1 : 0;
    __syncthreads();
    return r;
}

// ------- merged setup: weight transposes + voxel select/tokidx/validk + bias prep + flag -------
// blocks 0..3071: wtrans; 3072..3135: per-window meta (tokidx, validk, wcnt); 3136..3141: bias.
// tokidx[n*512+s] = unique-token row (0..6143) feeding window n slot s (0 if invalid; masked).
__global__ __launch_bounds__(256) void setup_kernel(
    const void* __restrict__ wq, const void* __restrict__ wk,
    const void* __restrict__ wv, const void* __restrict__ wo,
    const void* __restrict__ w1, const void* __restrict__ w2,
    const void* __restrict__ bq, const void* __restrict__ bk, const void* __restrict__ bv,
    const void* __restrict__ patch,
    const int* __restrict__ vy, const int* __restrict__ vx,
    u16* __restrict__ wqkvT, u16* __restrict__ woT,
    u16* __restrict__ w1T, u16* __restrict__ w2T,
    float* __restrict__ bqkv, u16* __restrict__ tokidx, unsigned char* __restrict__ validk,
    int* __restrict__ wcnt, int* __restrict__ flagp)
{
    __shared__ int sm[256];
    __shared__ u16 tile[32][33];
    int tx = threadIdx.x, ty = threadIdx.y;          // block (32,8)
    int tid = ty * 32 + tx;
    int isbf = self_detect((const u32*)patch, tid, sm);
    int bid = blockIdx.x;
    if (bid == 0 && tid == 0) *flagp = isbf;

    if (bid < 3072) {
        int id = bid;
        const void* in; u16* out; int K, N; float sc = 1.f;
        if (id < 256)       { in = wq; out = wqkvT;              K = 512;  N = 512;  sc = 0.125f * LOG2E; }
        else if (id < 512)  { id -= 256;  in = wk; out = wqkvT + 512 * 512;  K = 512;  N = 512; }
        else if (id < 768)  { id -= 512;  in = wv; out = wqkvT + 1024 * 512; K = 512;  N = 512; }
        else if (id < 1024) { id -= 768;  in = wo; out = woT;    K = 512;  N = 512; }
        else if (id < 2048) { id -= 1024; in = w1; out = w1T;    K = 512;  N = 2048; }
        else                { id -= 2048; in = w2; out = w2T;    K = 2048; N = 512; }
        int ntx = N >> 5;
        int n0 = (id % ntx) * 32, k0 = (id / ntx) * 32;
        #pragma unroll
        for (int i = 0; i < 4; i++)
            tile[ty + i * 8][tx] = f2bf(sc * ldf(in, (size_t)(k0 + ty + i * 8) * N + (n0 + tx), isbf));
        __syncthreads();
        #pragma unroll
        for (int i = 0; i < 4; i++)
            out[(size_t)(n0 + ty + i * 8) * K + (k0 + tx)] = tile[tx][ty + i * 8];
    } else if (bid < 3136) {
        if (tid < 64) {                               // first wave only (64-lane ballot)
            int n = bid - 3072, lane = tid;
            int y0 = (n >> 3) << 3, x0 = (n & 7) << 3;
            int count = 0;
            for (int base = 0; base < NV_TOT; base += 64) {
                int v = base + lane;
                int yy = vy[v], xx = vx[v];
                bool m = (yy >= y0) && (yy < y0 + 16) && (xx >= x0) && (xx < x0 + 16);
                u64 mask = __ballot(m);
                int pos = count + __popcll(mask & ((1ull << lane) - 1ull));
                if (m && pos < VCAP) tokidx[n * S_TOK + A_TOK + pos] = (u16)(4096 + v);
                count += __popcll(mask);
            }
            int cn = count < VCAP ? count : VCAP;
            for (int j = lane; j < VCAP; j += 64) {
                if (j >= cn) tokidx[n * S_TOK + A_TOK + j] = 0;
                validk[n * S_TOK + A_TOK + j] = (j < cn) ? 1 : 0;
            }
            for (int s = lane; s < A_TOK; s += 64) {  // patch slots
                int iy = ((n >> 3) << 3) + (s >> 4);
                int ix = ((n & 7) << 3) + (s & 15);
                bool val = (iy < P_DIM) && (ix < P_DIM);
                tokidx[n * S_TOK + s] = val ? (u16)(iy * P_DIM + ix) : 0;
                validk[n * S_TOK + s] = val ? 1 : 0;
            }
            if (lane == 0) wcnt[n] = cn;
        }
    } else {
        int t = (bid - 3136) * 256 + tid;             // q bias pre-scaled incl. log2(e)
        if (t < 512)       bqkv[t] = 0.125f * LOG2E * ldf(bq, t, isbf);
        else if (t < 1024) bqkv[t] = ldf(bk, t - 512, isbf);
        else if (t < 1536) bqkv[t] = ldf(bv, t - 1024, isbf);
    }
}

// ---------------- LN1 over UNIQUE tokens -> hU (bf16): rows 0..4095 patch, 4096..6143 voxel ----
__global__ __launch_bounds__(256) void ln1u_kernel(
    const void* __restrict__ patch, const void* __restrict__ vox,
    const void* __restrict__ g, const void* __restrict__ b,
    const int* __restrict__ flagp,
    u16* __restrict__ h)
{
    int isbf = *flagp;
    int r = blockIdx.x * 4 + (threadIdx.x >> 6);    // one wave per unique token
    int lane = threadIdx.x & 63;
    const void* tok = (r < 4096) ? patch : vox;
    size_t base = (r < 4096) ? (size_t)r * C_DIM : (size_t)(r - 4096) * C_DIM;
    float4 xa = ld4(tok, base + lane * 4, isbf);
    float4 xb = ld4(tok, base + 256 + lane * 4, isbf);
    float sum = xa.x + xa.y + xa.z + xa.w + xb.x + xb.y + xb.z + xb.w;
    float sq  = xa.x * xa.x + xa.y * xa.y + xa.z * xa.z + xa.w * xa.w
              + xb.x * xb.x + xb.y * xb.y + xb.z * xb.z + xb.w * xb.w;
    #pragma unroll
    for (int off = 32; off; off >>= 1) {
        sum += __shfl_xor(sum, off, 64);
        sq  += __shfl_xor(sq,  off, 64);
    }
    float mean = sum * (1.f / C_DIM);
    float var  = fmaxf(sq * (1.f / C_DIM) - mean * mean, 0.f);
    float rstd = rsqrtf(var + 1e-5f);
    float4 ga = ld4(g, lane * 4, isbf);
    float4 gb = ld4(g, 256 + lane * 4, isbf);
    float4 ba = ld4(b, lane * 4, isbf);
    float4 bb = ld4(b, 256 + lane * 4, isbf);
    uint2 wa, wb;
    wa.x = cvtpk((xa.x - mean) * rstd * ga.x + ba.x, (xa.y - mean) * rstd * ga.y + ba.y);
    wa.y = cvtpk((xa.z - mean) * rstd * ga.z + ba.z, (xa.w - mean) * rstd * ga.w + ba.w);
    wb.x = cvtpk((xb.x - mean) * rstd * gb.x + bb.x, (xb.y - mean) * rstd * gb.y + bb.y);
    wb.y = cvtpk((xb.z - mean) * rstd * gb.z + bb.z, (xb.w - mean) * rstd * gb.w + bb.w);
    ((uint2*)(h + (size_t)r * C_DIM))[lane]      = wa;
    ((uint2*)(h + (size_t)r * C_DIM))[lane + 64] = wb;
}

// ---------------- LN2 over bf16 rows -> bf16 ----------------
__global__ __launch_bounds__(256) void ln2_kernel(
    const u16* __restrict__ x,
    const void* __restrict__ g, const void* __restrict__ b,
    const int* __restrict__ flagp,
    u16* __restrict__ h2)
{
    int isbf = *flagp;
    int r = blockIdx.x * 4 + (threadIdx.x >> 6);
    int lane = threadIdx.x & 63;
    const u16* src = x + (size_t)r * C_DIM;
    float4 xa = bf4f(((const ushort4*)src)[lane]);
    float4 xb = bf4f(((const ushort4*)src)[lane + 64]);
    float sum = xa.x + xa.y + xa.z + xa.w + xb.x + xb.y + xb.z + xb.w;
    float sq  = xa.x * xa.x + xa.y * xa.y + xa.z * xa.z + xa.w * xa.w
              + xb.x * xb.x + xb.y * xb.y + xb.z * xb.z + xb.w * xb.w;
    #pragma unroll
    for (int off = 32; off; off >>= 1) {
        sum += __shfl_xor(sum, off, 64);
        sq  += __shfl_xor(sq,  off, 64);
    }
    float mean = sum * (1.f / C_DIM);
    float var  = fmaxf(sq * (1.f / C_DIM) - mean * mean, 0.f);
    float rstd = rsqrtf(var + 1e-5f);
    float4 ga = ld4(g, lane * 4, isbf);
    float4 gb = ld4(g, 256 + lane * 4, isbf);
    float4 ba = ld4(b, lane * 4, isbf);
    float4 bb = ld4(b, 256 + lane * 4, isbf);
    uint2 wa, wb;
    wa.x = cvtpk((xa.x - mean) * rstd * ga.x + ba.x, (xa.y - mean) * rstd * ga.y + ba.y);
    wa.y = cvtpk((xa.z - mean) * rstd * ga.z + ba.z, (xa.w - mean) * rstd * ga.w + ba.w);
    wb.x = cvtpk((xb.x - mean) * rstd * gb.x + bb.x, (xb.y - mean) * rstd * gb.y + bb.y);
    wb.y = cvtpk((xb.z - mean) * rstd * gb.z + bb.z, (xb.w - mean) * rstd * gb.w + bb.w);
    ((uint2*)(h2 + (size_t)r * C_DIM))[lane]      = wa;
    ((uint2*)(h2 + (size_t)r * C_DIM))[lane + 64] = wb;
}

// ---------------- generic bf16 MFMA GEMM: C = op(A @ B^T + bias), one TM x 128 tile/block -----
// Single-buffer 2-barrier K-loop (best measured structure at these short-K shapes).
// TM = tile rows (128 or 64). TM=64 halves per-block resources -> ~2x blocks/CU for the
// low-residency N=512 GEMMs (WO, MLP2). vtb path requires TM=128 (QKV only).
// __launch_bounds__ min-waves (measured win, r9): TM=128 -> 3 waves/SIMD; TM=64 -> 4.
#define GF_GELU      2
#define GF_RES_BF16  8    // += res (bf16, [M][N])
#define GF_RES_PATCH 16   // += gathered patch token (raw dtype), valid positions only
#define GF_QKV       32   // UNIQUE-token qkv: N=1536 -> q [4096][512] / k [6144][512] / v^T [512][6144]
#define GF_PATCHM    64   // m rows are compact patch rows: skip fully-OOB edge tiles

template<int FLAGS, int TM>
__global__ __launch_bounds__(256, TM == 64 ? 4 : 3) void gemm_kernel(
    const u16* __restrict__ A, const u16* __restrict__ BT,
    const void* __restrict__ bias,
    void* __restrict__ Cout, void* __restrict__ Cout2, void* __restrict__ Cout3,
    const void* __restrict__ resv,
    const int* __restrict__ flagp,
    int M, int N, int K, int ldc)
{
    constexpr int AI  = TM / 32;          // a-frag count per wave (4 or 2)
    constexpr int TMW = TM / 2;           // rows per wave-row-half (64 or 32)
    __shared__ u16 smem[(TM + 128) * 64]; // A tile TM*64 + B tile 128*64 (u16); epilogue reuse
    int tid = threadIdx.x;
    int nt, mt;
    int gx = gridDim.x, gy = gridDim.y;
    if ((gy & 7) == 0) {
        // XCD-local remap: linear id L (x fastest), xcd = L % 8 (round-robin heuristic).
        int L = blockIdx.x + gx * blockIdx.y;
        int c = L & 7, s = L >> 3;
        mt = c * (gy >> 3) + s / gx;
        nt = s % gx;
    } else { nt = blockIdx.x; mt = blockIdx.y; }
    int m0 = mt * TM, n0 = nt << 7;
    int region = (FLAGS & GF_QKV) ? (nt >> 2) : 0;   // 0:q 1:k 2:v^T
    if constexpr (FLAGS & GF_QKV) {
        if (region == 0 && m0 >= 4096) return;       // q only for unique patch tokens
    }
    if constexpr (FLAGS & GF_PATCHM) {
        constexpr int TPW = 256 / TM;                 // tiles per window
        int n = mt / TPW;                             // window index
        int lo = (mt % TPW) * TM;                     // first local row
        if ((n >> 3) == 7 && lo >= 128) return;       // fully-OOB edge tile, rows never consumed
    }
    int isbf = 0;
    if constexpr ((FLAGS & (GF_RES_PATCH)) || (!(FLAGS & GF_QKV))) isbf = *flagp;
    int w = tid >> 6, lane = tid & 63;
    int wr = (w >> 1) * TMW, wc = (w & 1) * 64;
    int l16 = lane & 15, quad = lane >> 4;
    u16* As = smem;
    u16* Bs = smem + TM * 64;
    bool vtb = (FLAGS & GF_QKV) && (region == 2);   // transposed-output block (TM=128 only)

    f32x4 acc[AI][4];
    #pragma unroll
    for (int i = 0; i < AI; i++)
        #pragma unroll
        for (int j = 0; j < 4; j++) { acc[i][j][0] = 0.f; acc[i][j][1] = 0.f; acc[i][j][2] = 0.f; acc[i][j][3] = 0.f; }

    int swz = (l16 & 7);                   // frag-read chunk swizzle key
    const u16* Xs = vtb ? Bs : As;         // first operand rows -> D rows
    const u16* Ys = vtb ? As : Bs;
    for (int k0 = 0; k0 < K; k0 += 64) {
        #pragma unroll
        for (int it = 0; it < AI; it++) {      // A: TM*8 chunk slots
            int c = (it * 4 + w) * 64 + lane;
            int row = c >> 3, phys = c & 7;
            int kc = phys ^ (row & 7);          // XOR swizzle: break 128B-stride bank aliasing
            gload16(A + (size_t)(m0 + row) * K + k0 + kc * 8, As + (size_t)c * 8);
        }
        #pragma unroll
        for (int it = 0; it < 4; it++) {        // B: 1024 chunk slots
            int c = (it * 4 + w) * 64 + lane;
            int row = c >> 3, phys = c & 7;
            int kc = phys ^ (row & 7);
            gload16(BT + (size_t)(n0 + row) * K + k0 + kc * 8, Bs + (size_t)c * 8);
        }
        __syncthreads();
        #pragma unroll
        for (int ks = 0; ks < 2; ks++) {
            bf16x8 a[AI], b[4];
            #pragma unroll
            for (int i = 0; i < AI; i++) {
                int chunk = (ks * 4 + quad) ^ swz;
                a[i] = *(const bf16x8*)&Xs[(wr + i * 16 + l16) * 64 + chunk * 8];
            }
            #pragma unroll
            for (int j = 0; j < 4; j++) {
                int chunk = (ks * 4 + quad) ^ swz;
                b[j] = *(const bf16x8*)&Ys[(wc + j * 16 + l16) * 64 + chunk * 8];
            }
            #pragma unroll
            for (int i = 0; i < AI; i++)
                #pragma unroll
                for (int j = 0; j < 4; j++)
                    acc[i][j] = __builtin_amdgcn_mfma_f32_16x16x32_bf16(a[i], b[j], acc[i][j], 0, 0, 0);
        }
        __syncthreads();
    }

    // ---------- epilogue (bf16 via cvt_pk, LDS-staged, coalesced 128B rows) ----------
    u16* st = smem + w * (TMW * 64);    // per-wave TMW x 64 bf16 stage (reuses tile LDS)
    #pragma unroll
    for (int i = 0; i < AI; i++) {
        #pragma unroll
        for (int j = 0; j < 4; j++) {
            int gcol = n0 + wc + j * 16 + l16;
            float bc = 0.f;
            if constexpr (FLAGS & GF_QKV) { if (!vtb) bc = ((const float*)bias)[gcol]; }
            else if (bias) bc = ldf(bias, gcol, isbf);
            float vv[4];
            #pragma unroll
            for (int r2 = 0; r2 < 4; r2++) {
                int lrow = wr + i * 16 + quad * 4 + r2;
                int grow = m0 + lrow;
                if (vtb) bc = ((const float*)bias)[n0 + lrow];   // channel-indexed bias
                float v = acc[i][j][r2] + bc;
                if constexpr (FLAGS & GF_GELU) v = fast_gelu(v);
                if constexpr (FLAGS & GF_RES_BF16) v += bf2f(((const u16*)resv)[(size_t)grow * N + gcol]);
                if constexpr (FLAGS & GF_RES_PATCH) {
                    int nn = grow >> 8, s = grow & 255;
                    int iy = ((nn >> 3) << 3) + (s >> 4);
                    int ix = ((nn & 7) << 3) + (s & 15);
                    if (iy < P_DIM && ix < P_DIM)
                        v += ldf(resv, (size_t)(iy * P_DIM + ix) * C_DIM + gcol, isbf);
                }
                vv[r2] = v;
            }
            u32 p01 = cvtpk(vv[0], vv[1]);
            u32 p23 = cvtpk(vv[2], vv[3]);
            int sb = (i * 16 + quad * 4) * 64 + j * 16 + l16;
            st[sb]       = (u16)p01;
            st[sb + 64]  = (u16)(p01 >> 16);
            st[sb + 128] = (u16)p23;
            st[sb + 192] = (u16)(p23 >> 16);
        }
    }
    asm volatile("" ::: "memory");   // same-wave LDS: block reorder, no barrier needed
    u16* cdst; int cst;
    if constexpr (FLAGS & GF_QKV) {
        if (region == 0) {          // q: unique patch-token rows, pre-scaled
            cst = 512;
            cdst = (u16*)Cout  + (size_t)(m0 + wr) * 512 + (n0 + wc);
        } else if (region == 1) {   // k: unique-token rows
            cst = 512;
            cdst = (u16*)Cout2 + (size_t)(m0 + wr) * 512 + (n0 - 512 + wc);
        } else {                    // v^T: rows = channels, cols = unique tokens
            cst = NUNIQ;
            cdst = (u16*)Cout3 + (size_t)(n0 - 1024 + wr) * NUNIQ + (m0 + wc);
        }
    } else {
        cst = ldc;
        cdst = (u16*)Cout + (size_t)(m0 + wr) * ldc + (n0 + wc);
    }
    #pragma unroll
    for (int rr = 0; rr < TM / 16; rr++) {
        int row = rr * 8 + (lane >> 3);
        uint4 val = *(const uint4*)&st[row * 64 + (lane & 7) * 8];
        *(uint4*)(cdst + (size_t)row * cst + (lane & 7) * 8) = val;   // 128B/row coalesced
    }
}

// ---------------- expand V^T unique -> window-major V^T [512][32768] ----------------
// d uniform per block -> vTU row (12KB) stays L1-resident; writes coalesced 16B/lane.
__global__ __launch_bounds__(256) void expandv_kernel(
    const u16* __restrict__ vTU, const u16* __restrict__ tokidx,
    u16* __restrict__ vtt)
{
    int gid = blockIdx.x * 256 + threadIdx.x;   // one uint4 (8 slots) per thread
    int d = gid >> 12;                          // 4096 chunks per channel row
    int c = gid & 4095;
    int n = c >> 6, s0 = (c & 63) * 8;
    const u16* tp = tokidx + n * S_TOK + s0;
    ushort4 ta = *(const ushort4*)tp;
    ushort4 tb = *(const ushort4*)(tp + 4);
    const u16* vr = vTU + (size_t)d * NUNIQ;
    uint4 val;
    val.x = (u32)vr[ta.x] | ((u32)vr[ta.y] << 16);
    val.y = (u32)vr[ta.z] | ((u32)vr[ta.w] << 16);
    val.z = (u32)vr[tb.x] | ((u32)vr[tb.y] << 16);
    val.w = (u32)vr[tb.z] | ((u32)vr[tb.w] << 16);
    *(uint4*)(vtt + (size_t)d * NROW + n * S_TOK + s0) = val;
}

// ---------------- flash attention per (window, head); patch queries only ----------------
// Q read at unique-token rows; K gathered per-lane from kU via tokidx (gload16 src is per-lane);
// V from window-major vtt. scores in log2 domain (log2e folded into q scale).
// No launch-bounds cap: live state (64 acc + qf + lsum) needs ~208 VGPR; capping to 170
// spills everything to scratch (measured r13: 287MB scratch writes, 4.5x slower).
__global__ __launch_bounds__(256) void attn_kernel(
    const u16* __restrict__ q, const u16* __restrict__ kU, const u16* __restrict__ vtg,
    const u16* __restrict__ tokidx,
    const unsigned char* __restrict__ validk, const int* __restrict__ wcnt,
    u16* __restrict__ o)
{
    __shared__ u16 sK[64 * 64];          // [key][d], DMA-gathered, swizzled chunks
    __shared__ u16 sV[64 * 64];          // [d][key], DMA-staged from V^T, swizzled chunks
    __shared__ u16 sP[4 * 64 * 64];      // per-wave P tile, chunk-swizzled (48KB total LDS)
    int h = blockIdx.x, n = blockIdx.y;
    int tid = threadIdx.x;
    int w = tid >> 6, lane = tid & 63;
    int l16 = lane & 15, quad = lane >> 4;
    int swz = (l16 & 7);
    int cnt = wcnt[n];                   // valid voxel slots in this window

    // prefetch this lane's K-row token ids for all 8 key-tiles (8 lanes share a row -> broadcast)
    int rowA = tid >> 3;                 // staging row for it=0 (c = tid)
    u16 tokA[8], tokB[8];
    #pragma unroll
    for (int t = 0; t < 8; t++) {
        tokA[t] = tokidx[n * S_TOK + t * 64 + rowA];
        tokB[t] = tokidx[n * S_TOK + t * 64 + 32 + rowA];
    }

    bf16x8 qf[4][2];
    #pragma unroll
    for (int i = 0; i < 4; i++)
        #pragma unroll
        for (int ks = 0; ks < 2; ks++) {
            int tok = tokidx[n * S_TOK + w * 64 + i * 16 + l16];   // patch slots (<256)
            int col = h * HDIM + ks * 32 + quad * 8;
            qf[i][ks] = *(const bf16x8*)(q + (size_t)tok * C_DIM + col);
        }

    f32x4 oacc[4][4];
    float lsum[4][4];
    #pragma unroll
    for (int i = 0; i < 4; i++)
        #pragma unroll
        for (int j = 0; j < 4; j++) {
            oacc[i][j][0] = 0.f; oacc[i][j][1] = 0.f; oacc[i][j][2] = 0.f; oacc[i][j][3] = 0.f;
            lsum[i][j] = 0.f;
        }

    for (int ktile = 0; ktile < 8; ktile++) {
        // voxel key-tiles past the valid count are entirely masked -> skip (block-uniform, monotone)
        if (ktile >= 4 && cnt <= (ktile - 4) * 64) break;
        __syncthreads();                       // prior tile's readers done before overwrite
        #pragma unroll
        for (int it = 0; it < 2; it++) {
            int c = it * 256 + w * 64 + lane;  // 0..511 chunk slots
            int row = c >> 3, phys = c & 7;
            int kc = phys ^ (row & 7);
            int tok = (it == 0) ? tokA[ktile] : tokB[ktile];
            gload16(kU + (size_t)tok * C_DIM + h * HDIM + kc * 8, sK + (size_t)c * 8);
            gload16(vtg + (size_t)(h * HDIM + row) * (size_t)NROW + n * S_TOK + ktile * 64 + kc * 8,
                    sV + (size_t)c * 8);
        }
        __syncthreads();

        f32x4 sacc[4][4];
        #pragma unroll
        for (int i = 0; i < 4; i++)
            #pragma unroll
            for (int j = 0; j < 4; j++) { sacc[i][j][0] = 0.f; sacc[i][j][1] = 0.f; sacc[i][j][2] = 0.f; sacc[i][j][3] = 0.f; }
        #pragma unroll
        for (int ks = 0; ks < 2; ks++) {
            int chunk = (ks * 4 + quad) ^ swz;
            bf16x8 bfr[4];
            #pragma unroll
            for (int j = 0; j < 4; j++) bfr[j] = *(const bf16x8*)&sK[(j * 16 + l16) * 64 + chunk * 8];
            #pragma unroll
            for (int i = 0; i < 4; i++)
                #pragma unroll
                for (int j = 0; j < 4; j++)
                    sacc[i][j] = __builtin_amdgcn_mfma_f32_16x16x32_bf16(qf[i][ks], bfr[j], sacc[i][j], 0, 0, 0);
        }

        bool kvalid[4];
        #pragma unroll
        for (int j = 0; j < 4; j++)
            kvalid[j] = validk[n * S_TOK + ktile * 64 + j * 16 + l16] != 0;

        #pragma unroll
        for (int i = 0; i < 4; i++)
            #pragma unroll
            for (int r2 = 0; r2 < 4; r2++) {
                int prow = i * 16 + quad * 4 + r2;
                float pv[4];
                #pragma unroll
                for (int j = 0; j < 4; j++) {
                    pv[j] = kvalid[j] ? exp2f(sacc[i][j][r2]) : 0.f;
                    lsum[i][r2] += pv[j];
                }
                #pragma unroll
                for (int jp = 0; jp < 2; jp++) {
                    u32 pk = cvtpk(pv[2 * jp], pv[2 * jp + 1]);
                    int col0 = (2 * jp) * 16 + l16;
                    int col1 = col0 + 16;
                    int base_ = (w * 64 + prow) * 64;
                    sP[base_ + (((col0 >> 3) ^ (prow & 7)) << 3) + (col0 & 7)] = (u16)pk;
                    sP[base_ + (((col1 >> 3) ^ (prow & 7)) << 3) + (col1 & 7)] = (u16)(pk >> 16);
                }
            }
        asm volatile("" ::: "memory");   // per-wave LDS: forbid read-before-write reorder
        #pragma unroll
        for (int ks = 0; ks < 2; ks++) {
            int chunk = (ks * 4 + quad) ^ swz;
            bf16x8 pa[4], vb[4];
            #pragma unroll
            for (int i = 0; i < 4; i++)   pa[i]  = *(const bf16x8*)&sP[(w * 64 + i * 16 + l16) * 64 + chunk * 8];
            #pragma unroll
            for (int jd = 0; jd < 4; jd++) vb[jd] = *(const bf16x8*)&sV[(jd * 16 + l16) * 64 + chunk * 8];
            #pragma unroll
            for (int i = 0; i < 4; i++)
                #pragma unroll
                for (int jd = 0; jd < 4; jd++)
                    oacc[i][jd] = __builtin_amdgcn_mfma_f32_16x16x32_bf16(pa[i], vb[jd], oacc[i][jd], 0, 0, 0);
        }
    }

    // normalize, stage O per-wave in LDS, coalesced 128B stores
    asm volatile("" ::: "memory");
    __syncthreads();                     // all waves done with sP/sV before O staging reuse
    u16* ost = sP + w * 4096;            // flat 64x64 region, stride 64 (sP data dead)
    #pragma unroll
    for (int i = 0; i < 4; i++) {
        #pragma unroll
        for (int r2 = 0; r2 < 4; r2++) {
            float l = lsum[i][r2];
            #pragma unroll
            for (int off = 8; off; off >>= 1)
                l += __shfl_xor(l, off, 64);
            float inv = (l > 0.f) ? 1.f / l : 0.f;
            int ob_ = (i * 16 + quad * 4 + r2) * 64 + l16;
            u32 q01 = cvtpk(oacc[i][0][r2] * inv, oacc[i][1][r2] * inv);
            u32 q23 = cvtpk(oacc[i][2][r2] * inv, oacc[i][3][r2] * inv);
            ost[ob_]      = (u16)q01;
            ost[ob_ + 16] = (u16)(q01 >> 16);
            ost[ob_ + 32] = (u16)q23;
            ost[ob_ + 48] = (u16)(q23 >> 16);
        }
    }
    asm volatile("" ::: "memory");
    u16* obase = o + (size_t)(n * A_TOK + w * 64) * C_DIM + h * HDIM;
    #pragma unroll
    for (int rr = 0; rr < 8; rr++) {
        int row = rr * 8 + (lane >> 3);
        uint4 val = *(const uint4*)&ost[row * 64 + (lane & 7) * 8];
        *(uint4*)(obase + (size_t)row * C_DIM + (lane & 7) * 8) = val;
    }
}

// ---------------- final gather-average (bf16 input) ----------------
__global__ __launch_bounds__(256) void gather_kernel(const u16* __restrict__ xf,
                                                     void* __restrict__ out,
                                                     const int* __restrict__ flagp)
{
    int isbf = *flagp;
    int gid = blockIdx.x * 256 + threadIdx.x;    // pixel*128 + 4-elem chunk
    int p = gid >> 7, cv = gid & 127;
    int py = p >> 6, px = p & 63;
    float4 acc = make_float4(0.f, 0.f, 0.f, 0.f);
    int cnt = 0;
    #pragma unroll
    for (int dy = 0; dy < 2; dy++) {
        int y0 = ((py >> 3) - dy) << 3;
        if (y0 < 0) continue;
        #pragma unroll
        for (int dx = 0; dx < 2; dx++) {
            int x0 = ((px >> 3) - dx) << 3;
            if (x0 < 0) continue;
            int n = ((y0 >> 3) << 3) + (x0 >> 3);
            int s = (py - y0) * 16 + (px - x0);
            float4 t = bf4f(((const ushort4*)(xf + (size_t)(n * A_TOK + s) * C_DIM))[cv]);
            acc.x += t.x; acc.y += t.y; acc.z += t.z; acc.w += t.w;
            cnt++;
        }
    }
    float inv = 1.f / (float)cnt;
    acc.x *= inv; acc.y *= inv; acc.z *= inv; acc.w *= inv;
    if (isbf) {
        uint2 o;
        o.x = cvtpk(acc.x, acc.y);
        o.y = cvtpk(acc.z, acc.w);
        ((uint2*)out)[gid] = o;
    } else {
        ((float4*)out)[gid] = acc;
    }
}

extern "C" void kernel_launch(void* const* d_in, const int* in_sizes, int n_in,
                              void* d_out, int out_size, void* d_ws, size_t ws_size,
                              hipStream_t stream)
{
    const void* patch = d_in[0];
    const void* vox   = d_in[1];
    const void* ln1g  = d_in[2];
    const void* ln1b  = d_in[3];
    const void* wq = d_in[4];  const void* bq = d_in[5];
    const void* wk = d_in[6];  const void* bk = d_in[7];
    const void* wv = d_in[8];  const void* bv = d_in[9];
    const void* wo = d_in[10]; const void* bo = d_in[11];
    const void* ln2g = d_in[12];
    const void* ln2b = d_in[13];
    const void* w1 = d_in[14]; const void* b1 = d_in[15];
    const void* w2 = d_in[16]; const void* b2 = d_in[17];
    const int* vpy = (const int*)d_in[18];
    const int* vpx = (const int*)d_in[19];

    const size_t MB = 1ull << 20;
    char* ws = (char*)d_ws;
    if (ws_size < 128 * MB) return;   // insufficient workspace -> visible failure

    // unique-token buffers (all dead before tbuf is written at MLP1)
    u16*  hU    = (u16*)(ws + 0);          // [6144][512] bf16, 6MB
    u16*  kU    = (u16*)(ws + 6 * MB);     // [6144][512] bf16, 6MB   (live thru attn)
    u16*  vTU   = (u16*)(ws + 12 * MB);    // [512][6144] bf16, 6MB   (dead after expand)
    u16*  qU    = (u16*)(ws + 18 * MB);    // [4096][512] bf16, 4MB   (live thru attn)
    u16*  vtt   = (u16*)(ws + 22 * MB);    // window V^T [512][32768] bf16, 32MB (live thru attn)
    u16*  tbuf  = (u16*)(ws + 0);          // [16384][2048] bf16, 64MB (MLP1->MLP2; overlays 0..54MB)
    u16*  obuf  = (u16*)(ws + 64 * MB);    // [16384][512] bf16, 16MB (attn->WO)
    u16*  xfbuf = (u16*)(ws + 64 * MB);    // 16MB (MLP2 out; obuf dead by then)
    u16*  xbuf16 = (u16*)(ws + 80 * MB);   // x residual, 16MB (WO->MLP2)
    u16*  h2buf = (u16*)(ws + 96 * MB);    // 16MB (ln2->MLP1)
    u16* wqkvT = (u16*)(ws + 112 * MB);    // [1536][512] bf16, 1.5MB (q rows pre-scaled)
    u16* woT  = (u16*)(ws + 114 * MB);     // [512][512], 0.5MB
    u16* w1T  = (u16*)(ws + 115 * MB);     // [2048][512], 2MB
    u16* w2T  = (u16*)(ws + 117 * MB);     // [512][2048], 2MB
    u16* tokidx = (u16*)(ws + 119 * MB);   // [32768] u16, 64KB
    unsigned char* validk = (unsigned char*)(ws + 119 * MB + 64 * 1024); // 32KB
    int* flagp = (int*)(ws + 119 * MB + 128 * 1024);
    float* bqkv = (float*)(ws + 119 * MB + 132 * 1024);  // [1536] f32
    int* wcnt = (int*)(ws + 119 * MB + 140 * 1024);      // [64] valid-voxel counts

    // merged setup: wtrans (3072) + per-window meta (64) + bias prep (6)
    setup_kernel<<<3142, dim3(32, 8), 0, stream>>>(wq, wk, wv, wo, w1, w2, bq, bk, bv,
        patch, vpy, vpx, wqkvT, woT, w1T, w2T, bqkv, tokidx, validk, wcnt, flagp);

    // LN1 on 6144 unique tokens only (was 32768 window slots)
    ln1u_kernel<<<NUNIQ / 4, 256, 0, stream>>>(patch, vox, ln1g, ln1b, flagp, hU);

    // fused QKV on unique tokens: M=6144, N=1536 -> grid (12, 48), XCD-local remap
    gemm_kernel<GF_QKV, 128><<<dim3(12, NUNIQ / 128), 256, 0, stream>>>(hU, wqkvT, bqkv,
        qU, kU, vTU, nullptr, flagp, NUNIQ, 1536, 512, 512);

    // expand V^T to window-major (only V needs materialized window layout)
    expandv_kernel<<<(C_DIM * NROW / 8) / 256, 256, 0, stream>>>(vTU, tokidx, vtt);

    // attn: best-measured config (256-thread, single-buffer 48KB, natural regalloc)
    attn_kernel<<<dim3(HEADS, NWIN), 256, 0, stream>>>(qU, kU, vtt, tokidx, validk, wcnt, obuf);

    // x = tokens(patch gather) + o @ wo + bo  -- TM=64: grid (4,256) = ~3.75 blocks/CU
    gemm_kernel<GF_RES_PATCH | GF_PATCHM, 64><<<dim3(4, NPATCH / 64), 256, 0, stream>>>(obuf, woT, bo,
        xbuf16, nullptr, nullptr, patch, flagp, NPATCH, 512, 512, 512);

    ln2_kernel<<<NPATCH / 4, 256, 0, stream>>>(xbuf16, ln2g, ln2b, flagp, h2buf);

    // MLP1: TM=128, launch-bounds min 3 waves/SIMD (measured: drops MLP1 out of top-5)
    gemm_kernel<GF_GELU | GF_PATCHM, 128><<<dim3(16, NPATCH / 128), 256, 0, stream>>>(h2buf, w1T, b1,
        tbuf, nullptr, nullptr, nullptr, flagp, NPATCH, 2048, 512, 2048);

    // MLP2: TM=64
    gemm_kernel<GF_RES_BF16 | GF_PATCHM, 64><<<dim3(4, NPATCH / 64), 256, 0, stream>>>(tbuf, w2T, b2,
        xfbuf, nullptr, nullptr, xbuf16, flagp, NPATCH, 512, 2048, 512);

    gather_kernel<<<(4096 * 128) / 256, 256, 0, stream>>>(xfbuf, d_out, flagp);
}

// Round 15
// 331.727 us; speedup vs baseline: 1.6636x; 1.0325x over previous
//
#include <hip/hip_runtime.h>
#include <math.h>

using u16 = unsigned short;
using u32 = unsigned int;
using u64 = unsigned long long;
using bf16x8 = __attribute__((ext_vector_type(8))) short;
using f32x4  = __attribute__((ext_vector_type(4))) float;

#define C_DIM   512
#define HEADS   8
#define HDIM    64
#define P_DIM   64
#define A_TOK   256
#define VCAP    256
#define S_TOK   512
#define NWIN    64
#define NROW    32768      // NWIN * S_TOK (window-slot space)
#define NPATCH  16384      // NWIN * A_TOK
#define NUNIQ   6144       // 4096 patch + 2048 voxel unique tokens
#define MLP_DIM 2048
#define NV_TOT  2048
#define LOG2E   1.44269504088896f

__device__ __forceinline__ float bf2f(u16 b) { return __uint_as_float(((u32)b) << 16); }
__device__ __forceinline__ u16 f2bf(float f) {
    u32 u = __float_as_uint(f);
    return (u16)((u + 0x7fffu + ((u >> 16) & 1u)) >> 16);   // RNE
}
// HW packed f32->bf16 RNE: dst.lo = bf16(lo), dst.hi = bf16(hi). 1 inst replaces ~8.
__device__ __forceinline__ u32 cvtpk(float lo, float hi) {
    u32 r;
    asm("v_cvt_pk_bf16_f32 %0, %1, %2" : "=v"(r) : "v"(lo), "v"(hi));
    return r;
}
__device__ __forceinline__ float4 bf4f(ushort4 v) {
    return make_float4(bf2f(v.x), bf2f(v.y), bf2f(v.z), bf2f(v.w));
}
// dtype-agnostic loads from RAW inputs: isbf=1 -> bf16, else f32
__device__ __forceinline__ float ldf(const void* p, size_t e, int isbf) {
    return isbf ? bf2f(((const u16*)p)[e]) : ((const float*)p)[e];
}
__device__ __forceinline__ float4 ld4(const void* p, size_t e, int isbf) {  // e % 4 == 0
    if (isbf) return bf4f(*(const ushort4*)((const u16*)p + e));
    return *(const float4*)((const float*)p + e);
}
// async global->LDS, 16B per lane; lds dest must be wave-uniform-base + lane*16
__device__ __forceinline__ void gload16(const u16* g, u16* l) {
    __builtin_amdgcn_global_load_lds(
        (const __attribute__((address_space(1))) u32*)g,
        (__attribute__((address_space(3))) u32*)l, 16, 0, 0);
}
// tanh-form GELU via sigmoid, log2e folded into poly, v_rcp instead of exact div.
// x*sigmoid(1.5957691x + 0.0713548x^3); |err| <= ~3e-4 (approx dominates rcp's ~1e-7)
__device__ __forceinline__ float fast_gelu(float x) {
    float x2 = x * x;
    float z = x * (-2.3021083f - 0.10294323f * x2);   // = -(1.5957691 + 0.0713548 x^2)*log2e
    float e = exp2f(z);                               // v_exp_f32
    return x * __builtin_amdgcn_rcpf(1.f + e);        // v_rcp_f32
}
// per-block dtype self-detection: vote on low-16-bits-as-bf16 plausibility (L2-resident scan)
__device__ __forceinline__ int self_detect(const u32* patch, int tid, int* sm)
{
    int cnt = 0;
    for (int i = tid; i < 4096; i += 256) {
        u32 w = patch[i];
        float a = fabsf(__uint_as_float((w & 0xffffu) << 16));
        if (a > 1e-8f && a < 1e4f) cnt++;
    }
    sm[tid] = cnt;
    __syncthreads();
    for (int o = 128; o; o >>= 1) { if (tid < o) sm[tid] += sm[tid + o]; __syncthreads(); }
    int r = (sm[0] > 2458) ? 1 : 0;
    __syncthreads();
    return r;
}

// ------- merged setup: weight transposes + voxel select/tokidx/validk + bias prep + flag -------
// blocks 0..3071: wtrans; 3072..3135: per-window meta (tokidx, validk, wcnt); 3136..3141: bias.
// tokidx[n*512+s] = unique-token row (0..6143) feeding window n slot s (0 if invalid; masked).
__global__ __launch_bounds__(256) void setup_kernel(
    const void* __restrict__ wq, const void* __restrict__ wk,
    const void* __restrict__ wv, const void* __restrict__ wo,
    const void* __restrict__ w1, const void* __restrict__ w2,
    const void* __restrict__ bq, const void* __restrict__ bk, const void* __restrict__ bv,
    const void* __restrict__ patch,
    const int* __restrict__ vy, const int* __restrict__ vx,
    u16* __restrict__ wqkvT, u16* __restrict__ woT,
    u16* __restrict__ w1T, u16* __restrict__ w2T,
    float* __restrict__ bqkv, u16* __restrict__ tokidx, unsigned char* __restrict__ validk,
    int* __restrict__ wcnt, int* __restrict__ flagp)
{
    __shared__ int sm[256];
    __shared__ u16 tile[32][33];
    int tx = threadIdx.x, ty = threadIdx.y;          // block (32,8)
    int tid = ty * 32 + tx;
    int isbf = self_detect((const u32*)patch, tid, sm);
    int bid = blockIdx.x;
    if (bid == 0 && tid == 0) *flagp = isbf;

    if (bid < 3072) {
        int id = bid;
        const void* in; u16* out; int K, N; float sc = 1.f;
        if (id < 256)       { in = wq; out = wqkvT;              K = 512;  N = 512;  sc = 0.125f * LOG2E; }
        else if (id < 512)  { id -= 256;  in = wk; out = wqkvT + 512 * 512;  K = 512;  N = 512; }
        else if (id < 768)  { id -= 512;  in = wv; out = wqkvT + 1024 * 512; K = 512;  N = 512; }
        else if (id < 1024) { id -= 768;  in = wo; out = woT;    K = 512;  N = 512; }
        else if (id < 2048) { id -= 1024; in = w1; out = w1T;    K = 512;  N = 2048; }
        else                { id -= 2048; in = w2; out = w2T;    K = 2048; N = 512; }
        int ntx = N >> 5;
        int n0 = (id % ntx) * 32, k0 = (id / ntx) * 32;
        #pragma unroll
        for (int i = 0; i < 4; i++)
            tile[ty + i * 8][tx] = f2bf(sc * ldf(in, (size_t)(k0 + ty + i * 8) * N + (n0 + tx), isbf));
        __syncthreads();
        #pragma unroll
        for (int i = 0; i < 4; i++)
            out[(size_t)(n0 + ty + i * 8) * K + (k0 + tx)] = tile[tx][ty + i * 8];
    } else if (bid < 3136) {
        if (tid < 64) {                               // first wave only (64-lane ballot)
            int n = bid - 3072, lane = tid;
            int y0 = (n >> 3) << 3, x0 = (n & 7) << 3;
            int count = 0;
            for (int base = 0; base < NV_TOT; base += 64) {
                int v = base + lane;
                int yy = vy[v], xx = vx[v];
                bool m = (yy >= y0) && (yy < y0 + 16) && (xx >= x0) && (xx < x0 + 16);
                u64 mask = __ballot(m);
                int pos = count + __popcll(mask & ((1ull << lane) - 1ull));
                if (m && pos < VCAP) tokidx[n * S_TOK + A_TOK + pos] = (u16)(4096 + v);
                count += __popcll(mask);
            }
            int cn = count < VCAP ? count : VCAP;
            for (int j = lane; j < VCAP; j += 64) {
                if (j >= cn) tokidx[n * S_TOK + A_TOK + j] = 0;
                validk[n * S_TOK + A_TOK + j] = (j < cn) ? 1 : 0;
            }
            for (int s = lane; s < A_TOK; s += 64) {  // patch slots
                int iy = ((n >> 3) << 3) + (s >> 4);
                int ix = ((n & 7) << 3) + (s & 15);
                bool val = (iy < P_DIM) && (ix < P_DIM);
                tokidx[n * S_TOK + s] = val ? (u16)(iy * P_DIM + ix) : 0;
                validk[n * S_TOK + s] = val ? 1 : 0;
            }
            if (lane == 0) wcnt[n] = cn;
        }
    } else {
        int t = (bid - 3136) * 256 + tid;             // q bias pre-scaled incl. log2(e)
        if (t < 512)       bqkv[t] = 0.125f * LOG2E * ldf(bq, t, isbf);
        else if (t < 1024) bqkv[t] = ldf(bk, t - 512, isbf);
        else if (t < 1536) bqkv[t] = ldf(bv, t - 1024, isbf);
    }
}

// ---------------- LN1 over UNIQUE tokens -> hU (bf16): rows 0..4095 patch, 4096..6143 voxel ----
__global__ __launch_bounds__(256) void ln1u_kernel(
    const void* __restrict__ patch, const void* __restrict__ vox,
    const void* __restrict__ g, const void* __restrict__ b,
    const int* __restrict__ flagp,
    u16* __restrict__ h)
{
    int isbf = *flagp;
    int r = blockIdx.x * 4 + (threadIdx.x >> 6);    // one wave per unique token
    int lane = threadIdx.x & 63;
    const void* tok = (r < 4096) ? patch : vox;
    size_t base = (r < 4096) ? (size_t)r * C_DIM : (size_t)(r - 4096) * C_DIM;
    float4 xa = ld4(tok, base + lane * 4, isbf);
    float4 xb = ld4(tok, base + 256 + lane * 4, isbf);
    float sum = xa.x + xa.y + xa.z + xa.w + xb.x + xb.y + xb.z + xb.w;
    float sq  = xa.x * xa.x + xa.y * xa.y + xa.z * xa.z + xa.w * xa.w
              + xb.x * xb.x + xb.y * xb.y + xb.z * xb.z + xb.w * xb.w;
    #pragma unroll
    for (int off = 32; off; off >>= 1) {
        sum += __shfl_xor(sum, off, 64);
        sq  += __shfl_xor(sq,  off, 64);
    }
    float mean = sum * (1.f / C_DIM);
    float var  = fmaxf(sq * (1.f / C_DIM) - mean * mean, 0.f);
    float rstd = rsqrtf(var + 1e-5f);
    float4 ga = ld4(g, lane * 4, isbf);
    float4 gb = ld4(g, 256 + lane * 4, isbf);
    float4 ba = ld4(b, lane * 4, isbf);
    float4 bb = ld4(b, 256 + lane * 4, isbf);
    uint2 wa, wb;
    wa.x = cvtpk((xa.x - mean) * rstd * ga.x + ba.x, (xa.y - mean) * rstd * ga.y + ba.y);
    wa.y = cvtpk((xa.z - mean) * rstd * ga.z + ba.z, (xa.w - mean) * rstd * ga.w + ba.w);
    wb.x = cvtpk((xb.x - mean) * rstd * gb.x + bb.x, (xb.y - mean) * rstd * gb.y + bb.y);
    wb.y = cvtpk((xb.z - mean) * rstd * gb.z + bb.z, (xb.w - mean) * rstd * gb.w + bb.w);
    ((uint2*)(h + (size_t)r * C_DIM))[lane]      = wa;
    ((uint2*)(h + (size_t)r * C_DIM))[lane + 64] = wb;
}

// ---------------- LN2 over bf16 rows -> bf16 ----------------
__global__ __launch_bounds__(256) void ln2_kernel(
    const u16* __restrict__ x,
    const void* __restrict__ g, const void* __restrict__ b,
    const int* __restrict__ flagp,
    u16* __restrict__ h2)
{
    int isbf = *flagp;
    int r = blockIdx.x * 4 + (threadIdx.x >> 6);
    int lane = threadIdx.x & 63;
    const u16* src = x + (size_t)r * C_DIM;
    float4 xa = bf4f(((const ushort4*)src)[lane]);
    float4 xb = bf4f(((const ushort4*)src)[lane + 64]);
    float sum = xa.x + xa.y + xa.z + xa.w + xb.x + xb.y + xb.z + xb.w;
    float sq  = xa.x * xa.x + xa.y * xa.y + xa.z * xa.z + xa.w * xa.w
              + xb.x * xb.x + xb.y * xb.y + xb.z * xb.z + xb.w * xb.w;
    #pragma unroll
    for (int off = 32; off; off >>= 1) {
        sum += __shfl_xor(sum, off, 64);
        sq  += __shfl_xor(sq,  off, 64);
    }
    float mean = sum * (1.f / C_DIM);
    float var  = fmaxf(sq * (1.f / C_DIM) - mean * mean, 0.f);
    float rstd = rsqrtf(var + 1e-5f);
    float4 ga = ld4(g, lane * 4, isbf);
    float4 gb = ld4(g, 256 + lane * 4, isbf);
    float4 ba = ld4(b, lane * 4, isbf);
    float4 bb = ld4(b, 256 + lane * 4, isbf);
    uint2 wa, wb;
    wa.x = cvtpk((xa.x - mean) * rstd * ga.x + ba.x, (xa.y - mean) * rstd * ga.y + ba.y);
    wa.y = cvtpk((xa.z - mean) * rstd * ga.z + ba.z, (xa.w - mean) * rstd * ga.w + ba.w);
    wb.x = cvtpk((xb.x - mean) * rstd * gb.x + bb.x, (xb.y - mean) * rstd * gb.y + bb.y);
    wb.y = cvtpk((xb.z - mean) * rstd * gb.z + bb.z, (xb.w - mean) * rstd * gb.w + bb.w);
    ((uint2*)(h2 + (size_t)r * C_DIM))[lane]      = wa;
    ((uint2*)(h2 + (size_t)r * C_DIM))[lane + 64] = wb;
}

// ---------------- generic bf16 MFMA GEMM: C = op(A @ B^T + bias), one TM x 128 tile/block -----
// Single-buffer 2-barrier K-loop (best measured structure at these short-K shapes).
// TM = tile rows (128 or 64). TM=64 halves per-block resources -> ~2x blocks/CU for the
// low-residency N=512 GEMMs (WO, MLP2). vtb path requires TM=128 (QKV only).
// __launch_bounds__ min-waves (measured win, r9): TM=128 -> 3 waves/SIMD; TM=64 -> 4.
#define GF_GELU      2
#define GF_RES_BF16  8    // += res (bf16, [M][N])
#define GF_RES_PATCH 16   // += gathered patch token (raw dtype), valid positions only
#define GF_QKV       32   // UNIQUE-token qkv: N=1536 -> q [4096][512] / k [6144][512] / v^T [512][6144]
#define GF_PATCHM    64   // m rows are compact patch rows: skip fully-OOB edge tiles

template<int FLAGS, int TM>
__global__ __launch_bounds__(256, TM == 64 ? 4 : 3) void gemm_kernel(
    const u16* __restrict__ A, const u16* __restrict__ BT,
    const void* __restrict__ bias,
    void* __restrict__ Cout, void* __restrict__ Cout2, void* __restrict__ Cout3,
    const void* __restrict__ resv,
    const int* __restrict__ flagp,
    int M, int N, int K, int ldc)
{
    constexpr int AI  = TM / 32;          // a-frag count per wave (4 or 2)
    constexpr int TMW = TM / 2;           // rows per wave-row-half (64 or 32)
    __shared__ u16 smem[(TM + 128) * 64]; // A tile TM*64 + B tile 128*64 (u16); epilogue reuse
    int tid = threadIdx.x;
    int nt, mt;
    int gx = gridDim.x, gy = gridDim.y;
    if ((gy & 7) == 0) {
        // XCD-local remap: linear id L (x fastest), xcd = L % 8 (round-robin heuristic).
        int L = blockIdx.x + gx * blockIdx.y;
        int c = L & 7, s = L >> 3;
        mt = c * (gy >> 3) + s / gx;
        nt = s % gx;
    } else { nt = blockIdx.x; mt = blockIdx.y; }
    int m0 = mt * TM, n0 = nt << 7;
    int region = (FLAGS & GF_QKV) ? (nt >> 2) : 0;   // 0:q 1:k 2:v^T
    if constexpr (FLAGS & GF_QKV) {
        if (region == 0 && m0 >= 4096) return;       // q only for unique patch tokens
    }
    if constexpr (FLAGS & GF_PATCHM) {
        constexpr int TPW = 256 / TM;                 // tiles per window
        int n = mt / TPW;                             // window index
        int lo = (mt % TPW) * TM;                     // first local row
        if ((n >> 3) == 7 && lo >= 128) return;       // fully-OOB edge tile, rows never consumed
    }
    int isbf = 0;
    if constexpr ((FLAGS & (GF_RES_PATCH)) || (!(FLAGS & GF_QKV))) isbf = *flagp;
    int w = tid >> 6, lane = tid & 63;
    int wr = (w >> 1) * TMW, wc = (w & 1) * 64;
    int l16 = lane & 15, quad = lane >> 4;
    u16* As = smem;
    u16* Bs = smem + TM * 64;
    bool vtb = (FLAGS & GF_QKV) && (region == 2);   // transposed-output block (TM=128 only)

    f32x4 acc[AI][4];
    #pragma unroll
    for (int i = 0; i < AI; i++)
        #pragma unroll
        for (int j = 0; j < 4; j++) { acc[i][j][0] = 0.f; acc[i][j][1] = 0.f; acc[i][j][2] = 0.f; acc[i][j][3] = 0.f; }

    int swz = (l16 & 7);                   // frag-read chunk swizzle key
    const u16* Xs = vtb ? Bs : As;         // first operand rows -> D rows
    const u16* Ys = vtb ? As : Bs;
    for (int k0 = 0; k0 < K; k0 += 64) {
        #pragma unroll
        for (int it = 0; it < AI; it++) {      // A: TM*8 chunk slots
            int c = (it * 4 + w) * 64 + lane;
            int row = c >> 3, phys = c & 7;
            int kc = phys ^ (row & 7);          // XOR swizzle: break 128B-stride bank aliasing
            gload16(A + (size_t)(m0 + row) * K + k0 + kc * 8, As + (size_t)c * 8);
        }
        #pragma unroll
        for (int it = 0; it < 4; it++) {        // B: 1024 chunk slots
            int c = (it * 4 + w) * 64 + lane;
            int row = c >> 3, phys = c & 7;
            int kc = phys ^ (row & 7);
            gload16(BT + (size_t)(n0 + row) * K + k0 + kc * 8, Bs + (size_t)c * 8);
        }
        __syncthreads();
        #pragma unroll
        for (int ks = 0; ks < 2; ks++) {
            bf16x8 a[AI], b[4];
            #pragma unroll
            for (int i = 0; i < AI; i++) {
                int chunk = (ks * 4 + quad) ^ swz;
                a[i] = *(const bf16x8*)&Xs[(wr + i * 16 + l16) * 64 + chunk * 8];
            }
            #pragma unroll
            for (int j = 0; j < 4; j++) {
                int chunk = (ks * 4 + quad) ^ swz;
                b[j] = *(const bf16x8*)&Ys[(wc + j * 16 + l16) * 64 + chunk * 8];
            }
            #pragma unroll
            for (int i = 0; i < AI; i++)
                #pragma unroll
                for (int j = 0; j < 4; j++)
                    acc[i][j] = __builtin_amdgcn_mfma_f32_16x16x32_bf16(a[i], b[j], acc[i][j], 0, 0, 0);
        }
        __syncthreads();
    }

    // ---------- epilogue (bf16 via cvt_pk, LDS-staged, coalesced 128B rows) ----------
    u16* st = smem + w * (TMW * 64);    // per-wave TMW x 64 bf16 stage (reuses tile LDS)
    #pragma unroll
    for (int i = 0; i < AI; i++) {
        #pragma unroll
        for (int j = 0; j < 4; j++) {
            int gcol = n0 + wc + j * 16 + l16;
            float bc = 0.f;
            if constexpr (FLAGS & GF_QKV) { if (!vtb) bc = ((const float*)bias)[gcol]; }
            else if (bias) bc = ldf(bias, gcol, isbf);
            float vv[4];
            #pragma unroll
            for (int r2 = 0; r2 < 4; r2++) {
                int lrow = wr + i * 16 + quad * 4 + r2;
                int grow = m0 + lrow;
                if (vtb) bc = ((const float*)bias)[n0 + lrow];   // channel-indexed bias
                float v = acc[i][j][r2] + bc;
                if constexpr (FLAGS & GF_GELU) v = fast_gelu(v);
                if constexpr (FLAGS & GF_RES_BF16) v += bf2f(((const u16*)resv)[(size_t)grow * N + gcol]);
                if constexpr (FLAGS & GF_RES_PATCH) {
                    int nn = grow >> 8, s = grow & 255;
                    int iy = ((nn >> 3) << 3) + (s >> 4);
                    int ix = ((nn & 7) << 3) + (s & 15);
                    if (iy < P_DIM && ix < P_DIM)
                        v += ldf(resv, (size_t)(iy * P_DIM + ix) * C_DIM + gcol, isbf);
                }
                vv[r2] = v;
            }
            u32 p01 = cvtpk(vv[0], vv[1]);
            u32 p23 = cvtpk(vv[2], vv[3]);
            int sb = (i * 16 + quad * 4) * 64 + j * 16 + l16;
            st[sb]       = (u16)p01;
            st[sb + 64]  = (u16)(p01 >> 16);
            st[sb + 128] = (u16)p23;
            st[sb + 192] = (u16)(p23 >> 16);
        }
    }
    asm volatile("" ::: "memory");   // same-wave LDS: block reorder, no barrier needed
    u16* cdst; int cst;
    if constexpr (FLAGS & GF_QKV) {
        if (region == 0) {          // q: unique patch-token rows, pre-scaled
            cst = 512;
            cdst = (u16*)Cout  + (size_t)(m0 + wr) * 512 + (n0 + wc);
        } else if (region == 1) {   // k: unique-token rows
            cst = 512;
            cdst = (u16*)Cout2 + (size_t)(m0 + wr) * 512 + (n0 - 512 + wc);
        } else {                    // v^T: rows = channels, cols = unique tokens
            cst = NUNIQ;
            cdst = (u16*)Cout3 + (size_t)(n0 - 1024 + wr) * NUNIQ + (m0 + wc);
        }
    } else {
        cst = ldc;
        cdst = (u16*)Cout + (size_t)(m0 + wr) * ldc + (n0 + wc);
    }
    #pragma unroll
    for (int rr = 0; rr < TM / 16; rr++) {
        int row = rr * 8 + (lane >> 3);
        uint4 val = *(const uint4*)&st[row * 64 + (lane & 7) * 8];
        *(uint4*)(cdst + (size_t)row * cst + (lane & 7) * 8) = val;   // 128B/row coalesced
    }
}

// ---------------- expand V^T unique -> window-major V^T [512][32768] ----------------
// d uniform per block -> vTU row (12KB) stays L1-resident; writes coalesced 16B/lane.
__global__ __launch_bounds__(256) void expandv_kernel(
    const u16* __restrict__ vTU, const u16* __restrict__ tokidx,
    u16* __restrict__ vtt)
{
    int gid = blockIdx.x * 256 + threadIdx.x;   // one uint4 (8 slots) per thread
    int d = gid >> 12;                          // 4096 chunks per channel row
    int c = gid & 4095;
    int n = c >> 6, s0 = (c & 63) * 8;
    const u16* tp = tokidx + n * S_TOK + s0;
    ushort4 ta = *(const ushort4*)tp;
    ushort4 tb = *(const ushort4*)(tp + 4);
    const u16* vr = vTU + (size_t)d * NUNIQ;
    uint4 val;
    val.x = (u32)vr[ta.x] | ((u32)vr[ta.y] << 16);
    val.y = (u32)vr[ta.z] | ((u32)vr[ta.w] << 16);
    val.z = (u32)vr[tb.x] | ((u32)vr[tb.y] << 16);
    val.w = (u32)vr[tb.z] | ((u32)vr[tb.w] << 16);
    *(uint4*)(vtt + (size_t)d * NROW + n * S_TOK + s0) = val;
}

// ---------------- flash attention per (window, head); patch queries only ----------------
// 8-WAVE / 32-Q-ROWS-PER-WAVE variant: same total work (8x16 MFMA/tile = 4x32), same LDS
// (48KB: sK 8 + sV 8 + sP 8x4KB), but per-wave live state HALVES (oacc[2][4]+qf[2][2]+lsum[2][4])
// -> target VGPR <=128 for 2 blocks/CU x 8 waves = 16 waves/CU (2x TLP vs the 208-VGPR pin).
// Natural allocation (no forced cap -- r13 showed capping spills catastrophically).
// Q read at unique-token rows; K gathered per-lane from kU via tokidx; V from window-major vtt.
// scores in log2 domain (log2e folded into q scale). Numerics identical to 4-wave version.
__global__ __launch_bounds__(512) void attn_kernel(
    const u16* __restrict__ q, const u16* __restrict__ kU, const u16* __restrict__ vtg,
    const u16* __restrict__ tokidx,
    const unsigned char* __restrict__ validk, const int* __restrict__ wcnt,
    u16* __restrict__ o)
{
    __shared__ u16 sK[64 * 64];          // [key][d], DMA-gathered, swizzled chunks (8KB)
    __shared__ u16 sV[64 * 64];          // [d][key], DMA-staged from V^T (8KB)
    __shared__ u16 sP[8 * 32 * 64];      // per-wave 32x64 P tile, chunk-swizzled (32KB)
    int h = blockIdx.x, n = blockIdx.y;
    int tid = threadIdx.x;               // 0..511
    int w = tid >> 6, lane = tid & 63;
    int l16 = lane & 15, quad = lane >> 4;
    int swz = (l16 & 7);
    int cnt = wcnt[n];                   // valid voxel slots in this window

    // staging-row token ids for all 8 key-tiles (c = tid covers rows 0..63, 8 lanes/row)
    int rowK = tid >> 3;
    u16 tokA[8];
    #pragma unroll
    for (int t = 0; t < 8; t++)
        tokA[t] = tokidx[n * S_TOK + t * 64 + rowK];

    bf16x8 qf[2][2];
    #pragma unroll
    for (int i = 0; i < 2; i++)
        #pragma unroll
        for (int ks = 0; ks < 2; ks++) {
            int tok = tokidx[n * S_TOK + w * 32 + i * 16 + l16];   // patch slots (<256)
            int col = h * HDIM + ks * 32 + quad * 8;
            qf[i][ks] = *(const bf16x8*)(q + (size_t)tok * C_DIM + col);
        }

    f32x4 oacc[2][4];
    float lsum[2][4];
    #pragma unroll
    for (int i = 0; i < 2; i++)
        #pragma unroll
        for (int j = 0; j < 4; j++) {
            oacc[i][j][0] = 0.f; oacc[i][j][1] = 0.f; oacc[i][j][2] = 0.f; oacc[i][j][3] = 0.f;
            lsum[i][j] = 0.f;
        }

    for (int ktile = 0; ktile < 8; ktile++) {
        // voxel key-tiles past the valid count are entirely masked -> skip (block-uniform, monotone)
        if (ktile >= 4 && cnt <= (ktile - 4) * 64) break;
        __syncthreads();                       // prior tile's readers done before overwrite
        {   // stage: 512 chunk slots each for K and V; exactly one per thread
            int c = tid;
            int row = c >> 3, phys = c & 7;
            int kc = phys ^ (row & 7);
            gload16(kU + (size_t)tokA[ktile] * C_DIM + h * HDIM + kc * 8, sK + (size_t)c * 8);
            gload16(vtg + (size_t)(h * HDIM + row) * (size_t)NROW + n * S_TOK + ktile * 64 + kc * 8,
                    sV + (size_t)c * 8);
        }
        __syncthreads();

        f32x4 sacc[2][4];
        #pragma unroll
        for (int i = 0; i < 2; i++)
            #pragma unroll
            for (int j = 0; j < 4; j++) { sacc[i][j][0] = 0.f; sacc[i][j][1] = 0.f; sacc[i][j][2] = 0.f; sacc[i][j][3] = 0.f; }
        #pragma unroll
        for (int ks = 0; ks < 2; ks++) {
            int chunk = (ks * 4 + quad) ^ swz;
            bf16x8 bfr[4];
            #pragma unroll
            for (int j = 0; j < 4; j++) bfr[j] = *(const bf16x8*)&sK[(j * 16 + l16) * 64 + chunk * 8];
            #pragma unroll
            for (int i = 0; i < 2; i++)
                #pragma unroll
                for (int j = 0; j < 4; j++)
                    sacc[i][j] = __builtin_amdgcn_mfma_f32_16x16x32_bf16(qf[i][ks], bfr[j], sacc[i][j], 0, 0, 0);
        }

        bool kvalid[4];
        #pragma unroll
        for (int j = 0; j < 4; j++)
            kvalid[j] = validk[n * S_TOK + ktile * 64 + j * 16 + l16] != 0;

        #pragma unroll
        for (int i = 0; i < 2; i++)
            #pragma unroll
            for (int r2 = 0; r2 < 4; r2++) {
                int prow = i * 16 + quad * 4 + r2;     // 0..31 within wave tile
                float pv[4];
                #pragma unroll
                for (int j = 0; j < 4; j++) {
                    pv[j] = kvalid[j] ? exp2f(sacc[i][j][r2]) : 0.f;
                    lsum[i][r2] += pv[j];
                }
                #pragma unroll
                for (int jp = 0; jp < 2; jp++) {
                    u32 pk = cvtpk(pv[2 * jp], pv[2 * jp + 1]);
                    int col0 = (2 * jp) * 16 + l16;
                    int col1 = col0 + 16;
                    int base_ = w * 2048 + prow * 64;
                    sP[base_ + (((col0 >> 3) ^ (prow & 7)) << 3) + (col0 & 7)] = (u16)pk;
                    sP[base_ + (((col1 >> 3) ^ (prow & 7)) << 3) + (col1 & 7)] = (u16)(pk >> 16);
                }
            }
        asm volatile("" ::: "memory");   // per-wave LDS: forbid read-before-write reorder
        #pragma unroll
        for (int ks = 0; ks < 2; ks++) {
            int chunk = (ks * 4 + quad) ^ swz;
            bf16x8 pa[2], vb[4];
            #pragma unroll
            for (int i = 0; i < 2; i++)
                pa[i] = *(const bf16x8*)&sP[w * 2048 + (i * 16 + l16) * 64 + chunk * 8];
            #pragma unroll
            for (int jd = 0; jd < 4; jd++)
                vb[jd] = *(const bf16x8*)&sV[(jd * 16 + l16) * 64 + chunk * 8];
            #pragma unroll
            for (int i = 0; i < 2; i++)
                #pragma unroll
                for (int jd = 0; jd < 4; jd++)
                    oacc[i][jd] = __builtin_amdgcn_mfma_f32_16x16x32_bf16(pa[i], vb[jd], oacc[i][jd], 0, 0, 0);
        }
    }

    // normalize, stage O per-wave in LDS (own sP region), coalesced 128B stores
    asm volatile("" ::: "memory");
    __syncthreads();                     // all waves done with sP/sV before O staging reuse
    u16* ost = sP + w * 2048;            // flat 32x64 region, stride 64 (sP data dead)
    #pragma unroll
    for (int i = 0; i < 2; i++) {
        #pragma unroll
        for (int r2 = 0; r2 < 4; r2++) {
            float l = lsum[i][r2];
            #pragma unroll
            for (int off = 8; off; off >>= 1)
                l += __shfl_xor(l, off, 64);
            float inv = (l > 0.f) ? 1.f / l : 0.f;
            int ob_ = (i * 16 + quad * 4 + r2) * 64 + l16;
            u32 q01 = cvtpk(oacc[i][0][r2] * inv, oacc[i][1][r2] * inv);
            u32 q23 = cvtpk(oacc[i][2][r2] * inv, oacc[i][3][r2] * inv);
            ost[ob_]      = (u16)q01;
            ost[ob_ + 16] = (u16)(q01 >> 16);
            ost[ob_ + 32] = (u16)q23;
            ost[ob_ + 48] = (u16)(q23 >> 16);
        }
    }
    asm volatile("" ::: "memory");
    u16* obase = o + (size_t)(n * A_TOK + w * 32) * C_DIM + h * HDIM;
    #pragma unroll
    for (int rr = 0; rr < 4; rr++) {
        int row = rr * 8 + (lane >> 3);
        uint4 val = *(const uint4*)&ost[row * 64 + (lane & 7) * 8];
        *(uint4*)(obase + (size_t)row * C_DIM + (lane & 7) * 8) = val;
    }
}

// ---------------- final gather-average (bf16 input) ----------------
__global__ __launch_bounds__(256) void gather_kernel(const u16* __restrict__ xf,
                                                     void* __restrict__ out,
                                                     const int* __restrict__ flagp)
{
    int isbf = *flagp;
    int gid = blockIdx.x * 256 + threadIdx.x;    // pixel*128 + 4-elem chunk
    int p = gid >> 7, cv = gid & 127;
    int py = p >> 6, px = p & 63;
    float4 acc = make_float4(0.f, 0.f, 0.f, 0.f);
    int cnt = 0;
    #pragma unroll
    for (int dy = 0; dy < 2; dy++) {
        int y0 = ((py >> 3) - dy) << 3;
        if (y0 < 0) continue;
        #pragma unroll
        for (int dx = 0; dx < 2; dx++) {
            int x0 = ((px >> 3) - dx) << 3;
            if (x0 < 0) continue;
            int n = ((y0 >> 3) << 3) + (x0 >> 3);
            int s = (py - y0) * 16 + (px - x0);
            float4 t = bf4f(((const ushort4*)(xf + (size_t)(n * A_TOK + s) * C_DIM))[cv]);
            acc.x += t.x; acc.y += t.y; acc.z += t.z; acc.w += t.w;
            cnt++;
        }
    }
    float inv = 1.f / (float)cnt;
    acc.x *= inv; acc.y *= inv; acc.z *= inv; acc.w *= inv;
    if (isbf) {
        uint2 o;
        o.x = cvtpk(acc.x, acc.y);
        o.y = cvtpk(acc.z, acc.w);
        ((uint2*)out)[gid] = o;
    } else {
        ((float4*)out)[gid] = acc;
    }
}

extern "C" void kernel_launch(void* const* d_in, const int* in_sizes, int n_in,
                              void* d_out, int out_size, void* d_ws, size_t ws_size,
                              hipStream_t stream)
{
    const void* patch = d_in[0];
    const void* vox   = d_in[1];
    const void* ln1g  = d_in[2];
    const void* ln1b  = d_in[3];
    const void* wq = d_in[4];  const void* bq = d_in[5];
    const void* wk = d_in[6];  const void* bk = d_in[7];
    const void* wv = d_in[8];  const void* bv = d_in[9];
    const void* wo = d_in[10]; const void* bo = d_in[11];
    const void* ln2g = d_in[12];
    const void* ln2b = d_in[13];
    const void* w1 = d_in[14]; const void* b1 = d_in[15];
    const void* w2 = d_in[16]; const void* b2 = d_in[17];
    const int* vpy = (const int*)d_in[18];
    const int* vpx = (const int*)d_in[19];

    const size_t MB = 1ull << 20;
    char* ws = (char*)d_ws;
    if (ws_size < 128 * MB) return;   // insufficient workspace -> visible failure

    // unique-token buffers (all dead before tbuf is written at MLP1)
    u16*  hU    = (u16*)(ws + 0);          // [6144][512] bf16, 6MB
    u16*  kU    = (u16*)(ws + 6 * MB);     // [6144][512] bf16, 6MB   (live thru attn)
    u16*  vTU   = (u16*)(ws + 12 * MB);    // [512][6144] bf16, 6MB   (dead after expand)
    u16*  qU    = (u16*)(ws + 18 * MB);    // [4096][512] bf16, 4MB   (live thru attn)
    u16*  vtt   = (u16*)(ws + 22 * MB);    // window V^T [512][32768] bf16, 32MB (live thru attn)
    u16*  tbuf  = (u16*)(ws + 0);          // [16384][2048] bf16, 64MB (MLP1->MLP2; overlays 0..54MB)
    u16*  obuf  = (u16*)(ws + 64 * MB);    // [16384][512] bf16, 16MB (attn->WO)
    u16*  xfbuf = (u16*)(ws + 64 * MB);    // 16MB (MLP2 out; obuf dead by then)
    u16*  xbuf16 = (u16*)(ws + 80 * MB);   // x residual, 16MB (WO->MLP2)
    u16*  h2buf = (u16*)(ws + 96 * MB);    // 16MB (ln2->MLP1)
    u16* wqkvT = (u16*)(ws + 112 * MB);    // [1536][512] bf16, 1.5MB (q rows pre-scaled)
    u16* woT  = (u16*)(ws + 114 * MB);     // [512][512], 0.5MB
    u16* w1T  = (u16*)(ws + 115 * MB);     // [2048][512], 2MB
    u16* w2T  = (u16*)(ws + 117 * MB);     // [512][2048], 2MB
    u16* tokidx = (u16*)(ws + 119 * MB);   // [32768] u16, 64KB
    unsigned char* validk = (unsigned char*)(ws + 119 * MB + 64 * 1024); // 32KB
    int* flagp = (int*)(ws + 119 * MB + 128 * 1024);
    float* bqkv = (float*)(ws + 119 * MB + 132 * 1024);  // [1536] f32
    int* wcnt = (int*)(ws + 119 * MB + 140 * 1024);      // [64] valid-voxel counts

    // merged setup: wtrans (3072) + per-window meta (64) + bias prep (6)
    setup_kernel<<<3142, dim3(32, 8), 0, stream>>>(wq, wk, wv, wo, w1, w2, bq, bk, bv,
        patch, vpy, vpx, wqkvT, woT, w1T, w2T, bqkv, tokidx, validk, wcnt, flagp);

    // LN1 on 6144 unique tokens only (was 32768 window slots)
    ln1u_kernel<<<NUNIQ / 4, 256, 0, stream>>>(patch, vox, ln1g, ln1b, flagp, hU);

    // fused QKV on unique tokens: M=6144, N=1536 -> grid (12, 48), XCD-local remap
    gemm_kernel<GF_QKV, 128><<<dim3(12, NUNIQ / 128), 256, 0, stream>>>(hU, wqkvT, bqkv,
        qU, kU, vTU, nullptr, flagp, NUNIQ, 1536, 512, 512);

    // expand V^T to window-major (only V needs materialized window layout)
    expandv_kernel<<<(C_DIM * NROW / 8) / 256, 256, 0, stream>>>(vTU, tokidx, vtt);

    // attn: 8-wave/32-row variant -- halved per-wave VGPR state, natural regalloc
    attn_kernel<<<dim3(HEADS, NWIN), 512, 0, stream>>>(qU, kU, vtt, tokidx, validk, wcnt, obuf);

    // x = tokens(patch gather) + o @ wo + bo  -- TM=64: grid (4,256) = ~3.75 blocks/CU
    gemm_kernel<GF_RES_PATCH | GF_PATCHM, 64><<<dim3(4, NPATCH / 64), 256, 0, stream>>>(obuf, woT, bo,
        xbuf16, nullptr, nullptr, patch, flagp, NPATCH, 512, 512, 512);

    ln2_kernel<<<NPATCH / 4, 256, 0, stream>>>(xbuf16, ln2g, ln2b, flagp, h2buf);

    // MLP1: TM=128, launch-bounds min 3 waves/SIMD (measured: drops MLP1 out of top-5)
    gemm_kernel<GF_GELU | GF_PATCHM, 128><<<dim3(16, NPATCH / 128), 256, 0, stream>>>(h2buf, w1T, b1,
        tbuf, nullptr, nullptr, nullptr, flagp, NPATCH, 2048, 512, 2048);

    // MLP2: TM=64
    gemm_kernel<GF_RES_BF16 | GF_PATCHM, 64><<<dim3(4, NPATCH / 64), 256, 0, stream>>>(tbuf, w2T, b2,
        xfbuf, nullptr, nullptr, xbuf16, flagp, NPATCH, 512, 2048, 512);

    gather_kernel<<<(4096 * 128) / 256, 256, 0, stream>>>(xfbuf, d_out, flagp);
}